// Round 20
// baseline (791.728 us; speedup 1.0000x reference)
//
#include <hip/hip_runtime.h>
#include <cstdint>
#include <math.h>

// Problem constants (match reference)
#define N_ATOMS 30000
#define E_EDGES 200000
#define T_TRI   400000
#define D_DIM   128
#define H_HEADS 8
#define F_FEAT  16
#define CLS     6

typedef __attribute__((ext_vector_type(8))) short bf16x8;
typedef __attribute__((ext_vector_type(4))) float f32x4;

// bf16 helpers (RNE pack, bit-shift unpack)
static __device__ __forceinline__ unsigned short f2bf(float f) {
    union { float f; unsigned u; } v; v.f = f;
    unsigned r = v.u + 0x7FFFu + ((v.u >> 16) & 1u);
    return (unsigned short)(r >> 16);
}
static __device__ __forceinline__ void bf2x(unsigned u, float& a, float& b) {
    union { unsigned u; float f; } x, y;
    x.u = u << 16; y.u = u & 0xFFFF0000u;
    a = x.f; b = y.f;
}

// ---------------------------------------------------------------------------
// Kernel 1: 6-row angle MLP -> ae_table[6][128]
// ---------------------------------------------------------------------------
__launch_bounds__(256)
__global__ void ang_mlp_kernel(const float* __restrict__ tab,
                               const float* __restrict__ W0, const float* __restrict__ b0,
                               const float* __restrict__ W1, const float* __restrict__ b1,
                               const float* __restrict__ W2, const float* __restrict__ b2,
                               float* __restrict__ out)
{
    __shared__ float bufA[CLS * D_DIM];
    __shared__ float bufB[CLS * D_DIM];
    __shared__ float Wl[D_DIM * D_DIM];
    const int tid = threadIdx.x;
    for (int i = tid; i < CLS * D_DIM; i += 256) bufA[i] = tab[i];
    const float* Ws[3] = {W0, W1, W2};
    const float* bs[3] = {b0, b1, b2};
    float* in  = bufA;
    float* ob  = bufB;
    for (int l = 0; l < 3; ++l) {
        __syncthreads();
        for (int i = tid * 4; i < D_DIM * D_DIM; i += 256 * 4)
            *(float4*)&Wl[i] = *(const float4*)&Ws[l][i];
        __syncthreads();
        for (int o = tid; o < CLS * D_DIM; o += 256) {
            const int r = o >> 7, c = o & 127;
            float acc = bs[l][c];
            #pragma unroll 8
            for (int k = 0; k < D_DIM; ++k) acc += in[r * D_DIM + k] * Wl[k * D_DIM + c];
            ob[o] = fmaxf(acc, 0.f);
        }
        float* t = in; in = ob; ob = t;
    }
    __syncthreads();
    for (int i = tid; i < CLS * D_DIM; i += 256) out[i] = in[i];
}

// ---------------------------------------------------------------------------
// Kernel 2: bins (with atan2(+0,-0) degenerate-sign fix) + per-edge count.
// ---------------------------------------------------------------------------
__launch_bounds__(256)
__global__ void tri_bins_kernel(const float* __restrict__ pos,
                                const int* __restrict__ idx_i,
                                const int* __restrict__ idx_j,
                                const int* __restrict__ idx_k,
                                const int* __restrict__ iji,
                                int* __restrict__ bins,
                                int* __restrict__ cnt)
{
    const int t = blockIdx.x * 256 + threadIdx.x;
    if (t >= T_TRI) return;
    const int ii = idx_i[t], jj = idx_j[t], kk = idx_k[t];
    const float pix = pos[3*ii], piy = pos[3*ii+1], piz = pos[3*ii+2];
    const float jx = __fsub_rn(pos[3*jj],   pix);
    const float jy = __fsub_rn(pos[3*jj+1], piy);
    const float jz = __fsub_rn(pos[3*jj+2], piz);
    const float kx = __fsub_rn(pos[3*kk],   pix);
    const float ky = __fsub_rn(pos[3*kk+1], piy);
    const float kz = __fsub_rn(pos[3*kk+2], piz);
    const float a  = __fadd_rn(__fadd_rn(__fmul_rn(jx,kx), __fmul_rn(jy,ky)),
                               __fmul_rn(jz,kz));
    const float cx = __fsub_rn(__fmul_rn(jy,kz), __fmul_rn(jz,ky));
    const float cy = __fsub_rn(__fmul_rn(jz,kx), __fmul_rn(jx,kz));
    const float cz = __fsub_rn(__fmul_rn(jx,ky), __fmul_rn(jy,kx));
    const float ss = __fadd_rn(__fadd_rn(__fmul_rn(cx,cx), __fmul_rn(cy,cy)),
                               __fmul_rn(cz,cz));
    const float b  = __fsqrt_rn(ss);

    int bin;
    if (b == 0.0f && __float_as_uint(a) == 0x80000000u) {
        bin = 0;   // atan2(+0,-0): IEEE pi (bin 5) vs reference SVML 0 (bin 0)
    } else {
        const float angle = (float)atan2((double)b, (double)a);
        const float c = (float)(3.1415926 / 6.0);
        const float q = __fdiv_rn(angle, c);
        bin = (int)q;
        bin = bin < 0 ? 0 : (bin > CLS - 1 ? CLS - 1 : bin);
    }
    bins[t] = bin;
    atomicAdd(&cnt[iji[t]], 1);
}

// ---------------------------------------------------------------------------
// CSR build: block-scan (3 kernels) + scatter fill
// ---------------------------------------------------------------------------
__launch_bounds__(256)
__global__ void scan1_kernel(const int* __restrict__ cnt, int* __restrict__ offs,
                             int* __restrict__ bsum)
{
    __shared__ int buf[256];
    const int i = blockIdx.x * 256 + threadIdx.x;
    const int v = (i < E_EDGES) ? cnt[i] : 0;
    buf[threadIdx.x] = v;
    __syncthreads();
    for (int o = 1; o < 256; o <<= 1) {
        const int t = (threadIdx.x >= o) ? buf[threadIdx.x - o] : 0;
        __syncthreads();
        buf[threadIdx.x] += t;
        __syncthreads();
    }
    if (i < E_EDGES) offs[i] = buf[threadIdx.x] - v;
    if (threadIdx.x == 255) bsum[blockIdx.x] = buf[255];
}

__launch_bounds__(1024)
__global__ void scan2_kernel(int* __restrict__ bsum, int nb)
{
    __shared__ int buf[1024];
    const int tid = threadIdx.x;
    const int v = (tid < nb) ? bsum[tid] : 0;
    buf[tid] = v;
    __syncthreads();
    for (int o = 1; o < 1024; o <<= 1) {
        const int t = (tid >= o) ? buf[tid - o] : 0;
        __syncthreads();
        buf[tid] += t;
        __syncthreads();
    }
    if (tid < nb) bsum[tid] = buf[tid] - v;   // exclusive
}

__launch_bounds__(256)
__global__ void scan3_kernel(int* __restrict__ offs, const int* __restrict__ bsum)
{
    const int i = blockIdx.x * 256 + threadIdx.x;
    if (i < E_EDGES) offs[i] += bsum[blockIdx.x];
}

__launch_bounds__(256)
__global__ void fill_kernel(const int* __restrict__ iji, const int* __restrict__ offs,
                            int* __restrict__ cur, int* __restrict__ slot)
{
    const int t = blockIdx.x * 256 + threadIdx.x;
    if (t >= T_TRI) return;
    const int e = iji[t];
    const int p = offs[e] + atomicAdd(&cur[e], 1);
    slot[p] = t;
}

// ---------------------------------------------------------------------------
// Weight convert: Wt[384][128] = [kW|qW|vW]^T bf16;  W1t[256][128], W2t[128][256]
// ---------------------------------------------------------------------------
__launch_bounds__(256)
__global__ void conv_w_kernel(const float* __restrict__ kW, const float* __restrict__ qW,
                              const float* __restrict__ vW,
                              const float* __restrict__ W1, const float* __restrict__ W2,
                              unsigned short* __restrict__ Wt,
                              unsigned short* __restrict__ W1t,
                              unsigned short* __restrict__ W2t)
{
    const int i = blockIdx.x * 256 + threadIdx.x;
    if (i < 384 * 128) {               // Wt[n][k]
        const int n = i >> 7, k = i & 127;
        const int sel = n >> 7, c = n & 127;
        const float* W = (sel == 0) ? kW : (sel == 1) ? qW : vW;
        Wt[i] = f2bf(W[k * 128 + c]);
    }
    if (i < 128 * 256) {
        { const int n = i >> 7, k = i & 127;  W1t[n * 128 + k] = f2bf(W1[k * 256 + n]); }
        { const int n = i >> 8, k = i & 255;  W2t[n * 256 + k] = f2bf(W2[k * 128 + n]); }
    }
}

// ---------------------------------------------------------------------------
// Fused K/Q/V projection (MFMA), inline f32->bf16 A conversion.
// Output: KVh[E][256] (K cols 0-127, V cols 128-255), Qh[E][128].
// ---------------------------------------------------------------------------
__launch_bounds__(256)
__global__ void proj_mfma(const float* __restrict__ bond,
                          const unsigned short* __restrict__ Wt,
                          unsigned short* __restrict__ KVh,
                          unsigned short* __restrict__ Qh)
{
    __shared__ unsigned short ms[64 * 392];   // pitch 392 breaks bank alias
    const int lane = threadIdx.x & 63, w = threadIdx.x >> 6;
    const int m0 = blockIdx.x * 64 + w * 16;
    const int lr = lane & 15, g = lane >> 4;
    f32x4 acc[24];
    #pragma unroll
    for (int n = 0; n < 24; ++n) acc[n] = (f32x4){0.f, 0.f, 0.f, 0.f};
    #pragma unroll
    for (int kk = 0; kk < 4; ++kk) {
        const int64_t ab = (int64_t)(m0 + lr) * 128 + kk * 32 + g * 8;
        const float4 f0 = *(const float4*)&bond[ab];
        const float4 f1 = *(const float4*)&bond[ab + 4];
        bf16x8 a;
        a[0] = (short)f2bf(f0.x); a[1] = (short)f2bf(f0.y);
        a[2] = (short)f2bf(f0.z); a[3] = (short)f2bf(f0.w);
        a[4] = (short)f2bf(f1.x); a[5] = (short)f2bf(f1.y);
        a[6] = (short)f2bf(f1.z); a[7] = (short)f2bf(f1.w);
        #pragma unroll
        for (int n = 0; n < 24; ++n) {
            const bf16x8 b = *(const bf16x8*)&Wt[(n * 16 + lr) * 128 + kk * 32 + g * 8];
            acc[n] = __builtin_amdgcn_mfma_f32_16x16x32_bf16(a, b, acc[n], 0, 0, 0);
        }
    }
    #pragma unroll
    for (int n = 0; n < 24; ++n)
        #pragma unroll
        for (int r = 0; r < 4; ++r)
            ms[(w * 16 + g * 4 + r) * 392 + n * 16 + lr] = f2bf(acc[n][r]);
    __syncthreads();
    // cols 0-127 = K -> KV[0..127]; 128-255 = Q -> Q; 256-383 = V -> KV[128..255]
    for (int idx = threadIdx.x; idx < 64 * 48; idx += 256) {
        const int row = idx / 48, c8 = (idx % 48) * 8;
        const int e = blockIdx.x * 64 + row;
        const uint4 v = *(const uint4*)&ms[row * 392 + c8];
        if (c8 < 128)       *(uint4*)&KVh[(int64_t)e * 256 + c8] = v;
        else if (c8 < 256)  *(uint4*)&Qh[(int64_t)e * 128 + (c8 - 128)] = v;
        else                *(uint4*)&KVh[(int64_t)e * 256 + 128 + (c8 - 256)] = v;
    }
}

// ---------------------------------------------------------------------------
// FUSED per-edge attention + aggregation + he + LN1 (-> bf16 h).
// K,V packed per-row in KVh for gather locality.
// ---------------------------------------------------------------------------
__launch_bounds__(256)
__global__ void edge_att_kernel(const unsigned short* __restrict__ KVh,
                                const unsigned short* __restrict__ Qh,
                                const float* __restrict__ aeT,
                                const int* __restrict__ bins,
                                const int* __restrict__ ikj,
                                const int* __restrict__ slot,
                                const int* __restrict__ offs,
                                const int* __restrict__ cnt,
                                const float* __restrict__ battn,
                                const float* __restrict__ disW,
                                const float* __restrict__ bond,
                                const float* __restrict__ g1,
                                const float* __restrict__ b1,
                                float* __restrict__ he,
                                unsigned short* __restrict__ hbf)
{
    __shared__ float aeL[CLS * D_DIM];
    for (int i = threadIdx.x; i < CLS * D_DIM; i += 256) aeL[i] = aeT[i];
    __syncthreads();
    const int wid  = threadIdx.x >> 6;
    const int lane = threadIdx.x & 63;
    const int e = blockIdx.x * 4 + wid;
    const int d0 = lane * 2;
    const int h  = lane >> 3;
    const float dw = disW[h];

    unsigned qw = *(const unsigned*)&Qh[(int64_t)e * D_DIM + d0];
    float q0, q1; bf2x(qw, q0, q1);

    float acc0 = 0.f, acc1 = 0.f, den = 0.f;
    const int start = offs[e], n = cnt[e];
    for (int s = 0; s < n; ++s) {
        const int t   = slot[start + s];
        const int ekj = ikj[t];
        const int bin = bins[t];
        const float ae0 = aeL[bin * D_DIM + d0];
        const float ae1 = aeL[bin * D_DIM + d0 + 1];
        const int64_t kvb = (int64_t)ekj * 256;
        unsigned kw = *(const unsigned*)&KVh[kvb + d0];
        unsigned vw = *(const unsigned*)&KVh[kvb + 128 + d0];
        float k0, k1; bf2x(kw, k0, k1);
        float pd = (k0 + ae0) * (q0 + ae0) + (k1 + ae1) * (q1 + ae1);
        pd += __shfl_xor(pd, 1);
        pd += __shfl_xor(pd, 2);
        pd += __shfl_xor(pd, 4);
        const float ex = expf(pd * 0.25f + battn[ekj] * dw);
        den += ex;
        float v0, v1; bf2x(vw, v0, v1);
        acc0 += ex * (v0 + ae0);
        acc1 += ex * (v1 + ae1);
    }
    const float inv = (den > 0.f) ? 1.f / den : 0.f;
    const int64_t base = (int64_t)e * D_DIM;
    const float x0 = acc0 * inv + bond[base + d0];
    const float x1 = acc1 * inv + bond[base + d0 + 1];
    he[base + d0]     = x0;
    he[base + d0 + 1] = x1;
    float sum = x0 + x1;
    #pragma unroll
    for (int o = 32; o > 0; o >>= 1) sum += __shfl_xor(sum, o);
    const float mean = sum * (1.f / 128.f);
    const float dx0 = x0 - mean, dx1 = x1 - mean;
    float var = dx0 * dx0 + dx1 * dx1;
    #pragma unroll
    for (int o = 32; o > 0; o >>= 1) var += __shfl_xor(var, o);
    const float rs = rsqrtf(var * (1.f / 128.f) + 1e-5f);
    const float h0v = dx0 * rs * g1[d0]     + b1[d0];
    const float h1v = dx1 * rs * g1[d0 + 1] + b1[d0 + 1];
    *(unsigned*)&hbf[base + d0] =
        (unsigned)f2bf(h0v) | ((unsigned)f2bf(h1v) << 16);
}

// ---------------------------------------------------------------------------
// FUSED FFN (GEMM1 -> LDS -> GEMM2) + residual + LN2 -> d_out.
// mid never touches HBM.  Each wave owns 16 rows end-to-end; the LDS
// staging (bf16 mid, then f32 C) is per-wave-disjoint.
// ---------------------------------------------------------------------------
__launch_bounds__(256)
__global__ void ffn_fused(const unsigned short* __restrict__ hbf,
                          const unsigned short* __restrict__ W1t,
                          const unsigned short* __restrict__ W2t,
                          const float* __restrict__ he,
                          const float* __restrict__ g2, const float* __restrict__ b2,
                          float* __restrict__ outp)
{
    __shared__ __align__(16) unsigned char lds[64 * 264 * 2];   // 33,792 B
    unsigned short* ms = (unsigned short*)lds;                  // [64][264] bf16
    float (*cs)[132] = (float(*)[132])lds;                      // [64][132] f32
    const int lane = threadIdx.x & 63, w = threadIdx.x >> 6;
    const int m0 = blockIdx.x * 64 + w * 16;
    const int lr = lane & 15, g = lane >> 4;

    // ---- GEMM1: mid = relu(h @ W1), 16 n-tiles, K=128 ----
    {
        f32x4 acc[16];
        #pragma unroll
        for (int n = 0; n < 16; ++n) acc[n] = (f32x4){0.f, 0.f, 0.f, 0.f};
        #pragma unroll
        for (int kk = 0; kk < 4; ++kk) {
            const bf16x8 a = *(const bf16x8*)&hbf[(int64_t)(m0 + lr) * 128 + kk * 32 + g * 8];
            #pragma unroll
            for (int n = 0; n < 16; ++n) {
                const bf16x8 b = *(const bf16x8*)&W1t[(n * 16 + lr) * 128 + kk * 32 + g * 8];
                acc[n] = __builtin_amdgcn_mfma_f32_16x16x32_bf16(a, b, acc[n], 0, 0, 0);
            }
        }
        #pragma unroll
        for (int n = 0; n < 16; ++n)
            #pragma unroll
            for (int r = 0; r < 4; ++r) {
                float v = acc[n][r];
                v = v > 0.f ? v : 0.f;
                ms[(w * 16 + g * 4 + r) * 264 + n * 16 + lr] = f2bf(v);
            }
    }
    __syncthreads();

    // ---- GEMM2: C = mid @ W2, 8 n-tiles, K=256 ----
    f32x4 acc2[8];
    #pragma unroll
    for (int n = 0; n < 8; ++n) acc2[n] = (f32x4){0.f, 0.f, 0.f, 0.f};
    #pragma unroll
    for (int kk = 0; kk < 8; ++kk) {
        const bf16x8 a = *(const bf16x8*)&ms[(w * 16 + lr) * 264 + kk * 32 + g * 8];
        #pragma unroll
        for (int n = 0; n < 8; ++n) {
            const bf16x8 b = *(const bf16x8*)&W2t[(n * 16 + lr) * 256 + kk * 32 + g * 8];
            acc2[n] = __builtin_amdgcn_mfma_f32_16x16x32_bf16(a, b, acc2[n], 0, 0, 0);
        }
    }
    __syncthreads();   // all ms reads done before cs overwrites the region
    #pragma unroll
    for (int n = 0; n < 8; ++n)
        #pragma unroll
        for (int r = 0; r < 4; ++r)
            cs[w * 16 + g * 4 + r][n * 16 + lr] = acc2[n][r];
    __syncthreads();

    // ---- residual + LN2 on the wave's own 16 rows ----
    for (int i = 0; i < 16; ++i) {
        const int row = w * 16 + i;
        const int64_t rg = (int64_t)(blockIdx.x * 64 + row) * 128;
        float x0 = cs[row][lane]      + he[rg + lane];
        float x1 = cs[row][64 + lane] + he[rg + 64 + lane];
        float s = x0 + x1;
        #pragma unroll
        for (int o = 32; o > 0; o >>= 1) s += __shfl_xor(s, o);
        const float mean = s * (1.f / 128.f);
        const float d0 = x0 - mean, d1 = x1 - mean;
        float v = d0 * d0 + d1 * d1;
        #pragma unroll
        for (int o = 32; o > 0; o >>= 1) v += __shfl_xor(v, o);
        const float rs = rsqrtf(v * (1.f / 128.f) + 1e-5f);
        outp[rg + lane]      = d0 * rs * g2[lane]      + b2[lane];
        outp[rg + 64 + lane] = d1 * rs * g2[lane + 64] + b2[lane + 64];
    }
}

// ---------------------------------------------------------------------------
extern "C" void kernel_launch(void* const* d_in, const int* in_sizes, int n_in,
                              void* d_out, int out_size, void* d_ws, size_t ws_size,
                              hipStream_t stream)
{
    const float* bond     = (const float*)d_in[0];
    const float* pos      = (const float*)d_in[1];
    const float* battn    = (const float*)d_in[2];
    const float* ang_tab  = (const float*)d_in[3];
    const float* ang_in_W = (const float*)d_in[4];
    const float* ang_in_b = (const float*)d_in[5];
    const float* ang2_W   = (const float*)d_in[6];
    const float* ang2_b   = (const float*)d_in[7];
    const float* ang1_W   = (const float*)d_in[8];
    const float* ang1_b   = (const float*)d_in[9];
    const float* k_W      = (const float*)d_in[10];
    const float* q_W      = (const float*)d_in[11];
    const float* v_W      = (const float*)d_in[12];
    const float* dis_W    = (const float*)d_in[13];
    const float* ffn_W1   = (const float*)d_in[14];
    const float* ffn_W2   = (const float*)d_in[15];
    const float* ln1_g    = (const float*)d_in[16];
    const float* ln1_b    = (const float*)d_in[17];
    const float* ln2_g    = (const float*)d_in[18];
    const float* ln2_b    = (const float*)d_in[19];
    const int*   index_kj = (const int*)d_in[20];
    const int*   index_ji = (const int*)d_in[21];
    const int*   idx_i    = (const int*)d_in[22];
    const int*   idx_j    = (const int*)d_in[23];
    const int*   idx_k    = (const int*)d_in[24];

    float* ws = (float*)d_ws;
    // ws layout (float offsets) — ~211 MB, no overlaps
    int*            bins  = (int*)(ws + 0);          //   400,000
    int*            slot  = (int*)(ws + 400000);     //   400,000
    int*            offs  = (int*)(ws + 800000);     //   200,000
    int*            cnt   = (int*)(ws + 1000000);    //   200,000
    int*            cur   = (int*)(ws + 1200000);    //   200,000
    int*            bsum  = (int*)(ws + 1400000);    //     1,024
    float*          aeT   = ws + 1401088;            //       768
    unsigned short* W1t   = (unsigned short*)(ws + 1401856);   // 32,768 us
    unsigned short* W2t   = (unsigned short*)(ws + 1418240);   // 32,768 us
    unsigned short* Wt    = (unsigned short*)(ws + 1434624);   // 49,152 us
    float*          heb   = ws + 1459200;            // 25,600,000
    unsigned short* hbf   = (unsigned short*)(ws + 27059200); // 25.6M us
    unsigned short* Qh    = (unsigned short*)(ws + 39859200); // 25.6M us

    // d_out holds KVh (E x 256 bf16 = exactly out bytes), then final out
    unsigned short* KVh = (unsigned short*)d_out;
    float*          out = (float*)d_out;

    hipMemsetAsync(cnt, 0, (size_t)E_EDGES * sizeof(int), stream);
    hipMemsetAsync(cur, 0, (size_t)E_EDGES * sizeof(int), stream);

    ang_mlp_kernel<<<1, 256, 0, stream>>>(ang_tab, ang_in_W, ang_in_b,
                                          ang2_W, ang2_b, ang1_W, ang1_b, aeT);
    conv_w_kernel<<<192, 256, 0, stream>>>(k_W, q_W, v_W, ffn_W1, ffn_W2, Wt, W1t, W2t);
    tri_bins_kernel<<<(T_TRI + 255) / 256, 256, 0, stream>>>(
        pos, idx_i, idx_j, idx_k, index_ji, bins, cnt);

    const int NB = (E_EDGES + 255) / 256;    // 782
    scan1_kernel<<<NB, 256, 0, stream>>>(cnt, offs, bsum);
    scan2_kernel<<<1, 1024, 0, stream>>>(bsum, NB);
    scan3_kernel<<<NB, 256, 0, stream>>>(offs, bsum);
    fill_kernel<<<(T_TRI + 255) / 256, 256, 0, stream>>>(index_ji, offs, cur, slot);

    proj_mfma<<<E_EDGES / 64, 256, 0, stream>>>(bond, Wt, KVh, Qh);

    edge_att_kernel<<<E_EDGES / 4, 256, 0, stream>>>(
        KVh, Qh, aeT, bins, index_kj, slot, offs, cnt,
        battn, dis_W, bond, ln1_g, ln1_b, heb, hbf);

    ffn_fused<<<E_EDGES / 64, 256, 0, stream>>>(hbf, W1t, W2t, heb, ln2_g, ln2_b, out);
}

// Round 21
// 751.289 us; speedup vs baseline: 1.0538x; 1.0538x over previous
//
#include <hip/hip_runtime.h>
#include <cstdint>
#include <math.h>

// Problem constants (match reference)
#define N_ATOMS 30000
#define E_EDGES 200000
#define T_TRI   400000
#define D_DIM   128
#define H_HEADS 8
#define F_FEAT  16
#define CLS     6

typedef __attribute__((ext_vector_type(8))) short bf16x8;
typedef __attribute__((ext_vector_type(4))) float f32x4;

// bf16 helpers (RNE pack, bit-shift unpack)
static __device__ __forceinline__ unsigned short f2bf(float f) {
    union { float f; unsigned u; } v; v.f = f;
    unsigned r = v.u + 0x7FFFu + ((v.u >> 16) & 1u);
    return (unsigned short)(r >> 16);
}
static __device__ __forceinline__ void bf2x(unsigned u, float& a, float& b) {
    union { unsigned u; float f; } x, y;
    x.u = u << 16; y.u = u & 0xFFFF0000u;
    a = x.f; b = y.f;
}

// ---------------------------------------------------------------------------
// Kernel 1: 6-row angle MLP -> ae_table[6][128]
// ---------------------------------------------------------------------------
__launch_bounds__(256)
__global__ void ang_mlp_kernel(const float* __restrict__ tab,
                               const float* __restrict__ W0, const float* __restrict__ b0,
                               const float* __restrict__ W1, const float* __restrict__ b1,
                               const float* __restrict__ W2, const float* __restrict__ b2,
                               float* __restrict__ out)
{
    __shared__ float bufA[CLS * D_DIM];
    __shared__ float bufB[CLS * D_DIM];
    __shared__ float Wl[D_DIM * D_DIM];
    const int tid = threadIdx.x;
    for (int i = tid; i < CLS * D_DIM; i += 256) bufA[i] = tab[i];
    const float* Ws[3] = {W0, W1, W2};
    const float* bs[3] = {b0, b1, b2};
    float* in  = bufA;
    float* ob  = bufB;
    for (int l = 0; l < 3; ++l) {
        __syncthreads();
        for (int i = tid * 4; i < D_DIM * D_DIM; i += 256 * 4)
            *(float4*)&Wl[i] = *(const float4*)&Ws[l][i];
        __syncthreads();
        for (int o = tid; o < CLS * D_DIM; o += 256) {
            const int r = o >> 7, c = o & 127;
            float acc = bs[l][c];
            #pragma unroll 8
            for (int k = 0; k < D_DIM; ++k) acc += in[r * D_DIM + k] * Wl[k * D_DIM + c];
            ob[o] = fmaxf(acc, 0.f);
        }
        float* t = in; in = ob; ob = t;
    }
    __syncthreads();
    for (int i = tid; i < CLS * D_DIM; i += 256) out[i] = in[i];
}

// ---------------------------------------------------------------------------
// Kernel 2: bins (with atan2(+0,-0) degenerate-sign fix) + per-edge count.
// ---------------------------------------------------------------------------
__launch_bounds__(256)
__global__ void tri_bins_kernel(const float* __restrict__ pos,
                                const int* __restrict__ idx_i,
                                const int* __restrict__ idx_j,
                                const int* __restrict__ idx_k,
                                const int* __restrict__ iji,
                                int* __restrict__ bins,
                                int* __restrict__ cnt)
{
    const int t = blockIdx.x * 256 + threadIdx.x;
    if (t >= T_TRI) return;
    const int ii = idx_i[t], jj = idx_j[t], kk = idx_k[t];
    const float pix = pos[3*ii], piy = pos[3*ii+1], piz = pos[3*ii+2];
    const float jx = __fsub_rn(pos[3*jj],   pix);
    const float jy = __fsub_rn(pos[3*jj+1], piy);
    const float jz = __fsub_rn(pos[3*jj+2], piz);
    const float kx = __fsub_rn(pos[3*kk],   pix);
    const float ky = __fsub_rn(pos[3*kk+1], piy);
    const float kz = __fsub_rn(pos[3*kk+2], piz);
    const float a  = __fadd_rn(__fadd_rn(__fmul_rn(jx,kx), __fmul_rn(jy,ky)),
                               __fmul_rn(jz,kz));
    const float cx = __fsub_rn(__fmul_rn(jy,kz), __fmul_rn(jz,ky));
    const float cy = __fsub_rn(__fmul_rn(jz,kx), __fmul_rn(jx,kz));
    const float cz = __fsub_rn(__fmul_rn(jx,ky), __fmul_rn(jy,kx));
    const float ss = __fadd_rn(__fadd_rn(__fmul_rn(cx,cx), __fmul_rn(cy,cy)),
                               __fmul_rn(cz,cz));
    const float b  = __fsqrt_rn(ss);

    int bin;
    if (b == 0.0f && __float_as_uint(a) == 0x80000000u) {
        bin = 0;   // atan2(+0,-0): IEEE pi (bin 5) vs reference SVML 0 (bin 0)
    } else {
        const float angle = (float)atan2((double)b, (double)a);
        const float c = (float)(3.1415926 / 6.0);
        const float q = __fdiv_rn(angle, c);
        bin = (int)q;
        bin = bin < 0 ? 0 : (bin > CLS - 1 ? CLS - 1 : bin);
    }
    bins[t] = bin;
    atomicAdd(&cnt[iji[t]], 1);
}

// ---------------------------------------------------------------------------
// CSR build: block-scan (3 kernels) + scatter fill
// ---------------------------------------------------------------------------
__launch_bounds__(256)
__global__ void scan1_kernel(const int* __restrict__ cnt, int* __restrict__ offs,
                             int* __restrict__ bsum)
{
    __shared__ int buf[256];
    const int i = blockIdx.x * 256 + threadIdx.x;
    const int v = (i < E_EDGES) ? cnt[i] : 0;
    buf[threadIdx.x] = v;
    __syncthreads();
    for (int o = 1; o < 256; o <<= 1) {
        const int t = (threadIdx.x >= o) ? buf[threadIdx.x - o] : 0;
        __syncthreads();
        buf[threadIdx.x] += t;
        __syncthreads();
    }
    if (i < E_EDGES) offs[i] = buf[threadIdx.x] - v;
    if (threadIdx.x == 255) bsum[blockIdx.x] = buf[255];
}

__launch_bounds__(1024)
__global__ void scan2_kernel(int* __restrict__ bsum, int nb)
{
    __shared__ int buf[1024];
    const int tid = threadIdx.x;
    const int v = (tid < nb) ? bsum[tid] : 0;
    buf[tid] = v;
    __syncthreads();
    for (int o = 1; o < 1024; o <<= 1) {
        const int t = (tid >= o) ? buf[tid - o] : 0;
        __syncthreads();
        buf[tid] += t;
        __syncthreads();
    }
    if (tid < nb) bsum[tid] = buf[tid] - v;   // exclusive
}

__launch_bounds__(256)
__global__ void scan3_kernel(int* __restrict__ offs, const int* __restrict__ bsum)
{
    const int i = blockIdx.x * 256 + threadIdx.x;
    if (i < E_EDGES) offs[i] += bsum[blockIdx.x];
}

__launch_bounds__(256)
__global__ void fill_kernel(const int* __restrict__ iji, const int* __restrict__ offs,
                            int* __restrict__ cur, int* __restrict__ slot)
{
    const int t = blockIdx.x * 256 + threadIdx.x;
    if (t >= T_TRI) return;
    const int e = iji[t];
    const int p = offs[e] + atomicAdd(&cur[e], 1);
    slot[p] = t;
}

// ---------------------------------------------------------------------------
// Weight convert: Wt[384][128] = [kW|qW|vW]^T bf16;  W1t[256][128], W2t[128][256]
// ---------------------------------------------------------------------------
__launch_bounds__(256)
__global__ void conv_w_kernel(const float* __restrict__ kW, const float* __restrict__ qW,
                              const float* __restrict__ vW,
                              const float* __restrict__ W1, const float* __restrict__ W2,
                              unsigned short* __restrict__ Wt,
                              unsigned short* __restrict__ W1t,
                              unsigned short* __restrict__ W2t)
{
    const int i = blockIdx.x * 256 + threadIdx.x;
    if (i < 384 * 128) {               // Wt[n][k]
        const int n = i >> 7, k = i & 127;
        const int sel = n >> 7, c = n & 127;
        const float* W = (sel == 0) ? kW : (sel == 1) ? qW : vW;
        Wt[i] = f2bf(W[k * 128 + c]);
    }
    if (i < 128 * 256) {
        { const int n = i >> 7, k = i & 127;  W1t[n * 128 + k] = f2bf(W1[k * 256 + n]); }
        { const int n = i >> 8, k = i & 255;  W2t[n * 256 + k] = f2bf(W2[k * 128 + n]); }
    }
}

// ---------------------------------------------------------------------------
// Fused K/Q/V projection (MFMA), inline f32->bf16 A conversion.
// Output: KVh[E][256] (K cols 0-127, V cols 128-255), Qh[E][128].
// ---------------------------------------------------------------------------
__launch_bounds__(256)
__global__ void proj_mfma(const float* __restrict__ bond,
                          const unsigned short* __restrict__ Wt,
                          unsigned short* __restrict__ KVh,
                          unsigned short* __restrict__ Qh)
{
    __shared__ unsigned short ms[64 * 392];   // pitch 392 breaks bank alias
    const int lane = threadIdx.x & 63, w = threadIdx.x >> 6;
    const int m0 = blockIdx.x * 64 + w * 16;
    const int lr = lane & 15, g = lane >> 4;
    f32x4 acc[24];
    #pragma unroll
    for (int n = 0; n < 24; ++n) acc[n] = (f32x4){0.f, 0.f, 0.f, 0.f};
    #pragma unroll
    for (int kk = 0; kk < 4; ++kk) {
        const int64_t ab = (int64_t)(m0 + lr) * 128 + kk * 32 + g * 8;
        const float4 f0 = *(const float4*)&bond[ab];
        const float4 f1 = *(const float4*)&bond[ab + 4];
        bf16x8 a;
        a[0] = (short)f2bf(f0.x); a[1] = (short)f2bf(f0.y);
        a[2] = (short)f2bf(f0.z); a[3] = (short)f2bf(f0.w);
        a[4] = (short)f2bf(f1.x); a[5] = (short)f2bf(f1.y);
        a[6] = (short)f2bf(f1.z); a[7] = (short)f2bf(f1.w);
        #pragma unroll
        for (int n = 0; n < 24; ++n) {
            const bf16x8 b = *(const bf16x8*)&Wt[(n * 16 + lr) * 128 + kk * 32 + g * 8];
            acc[n] = __builtin_amdgcn_mfma_f32_16x16x32_bf16(a, b, acc[n], 0, 0, 0);
        }
    }
    #pragma unroll
    for (int n = 0; n < 24; ++n)
        #pragma unroll
        for (int r = 0; r < 4; ++r)
            ms[(w * 16 + g * 4 + r) * 392 + n * 16 + lr] = f2bf(acc[n][r]);
    __syncthreads();
    // cols 0-127 = K -> KV[0..127]; 128-255 = Q -> Q; 256-383 = V -> KV[128..255]
    for (int idx = threadIdx.x; idx < 64 * 48; idx += 256) {
        const int row = idx / 48, c8 = (idx % 48) * 8;
        const int e = blockIdx.x * 64 + row;
        const uint4 v = *(const uint4*)&ms[row * 392 + c8];
        if (c8 < 128)       *(uint4*)&KVh[(int64_t)e * 256 + c8] = v;
        else if (c8 < 256)  *(uint4*)&Qh[(int64_t)e * 128 + (c8 - 128)] = v;
        else                *(uint4*)&KVh[(int64_t)e * 256 + 128 + (c8 - 256)] = v;
    }
}

// ---------------------------------------------------------------------------
// FUSED per-edge attention + aggregation + he + LN1 (-> bf16 h).
// K,V packed per-row in KVh for gather locality.
// ---------------------------------------------------------------------------
__launch_bounds__(256)
__global__ void edge_att_kernel(const unsigned short* __restrict__ KVh,
                                const unsigned short* __restrict__ Qh,
                                const float* __restrict__ aeT,
                                const int* __restrict__ bins,
                                const int* __restrict__ ikj,
                                const int* __restrict__ slot,
                                const int* __restrict__ offs,
                                const int* __restrict__ cnt,
                                const float* __restrict__ battn,
                                const float* __restrict__ disW,
                                const float* __restrict__ bond,
                                const float* __restrict__ g1,
                                const float* __restrict__ b1,
                                float* __restrict__ he,
                                unsigned short* __restrict__ hbf)
{
    __shared__ float aeL[CLS * D_DIM];
    for (int i = threadIdx.x; i < CLS * D_DIM; i += 256) aeL[i] = aeT[i];
    __syncthreads();
    const int wid  = threadIdx.x >> 6;
    const int lane = threadIdx.x & 63;
    const int e = blockIdx.x * 4 + wid;
    const int d0 = lane * 2;
    const int h  = lane >> 3;
    const float dw = disW[h];

    unsigned qw = *(const unsigned*)&Qh[(int64_t)e * D_DIM + d0];
    float q0, q1; bf2x(qw, q0, q1);

    float acc0 = 0.f, acc1 = 0.f, den = 0.f;
    const int start = offs[e], n = cnt[e];
    for (int s = 0; s < n; ++s) {
        const int t   = slot[start + s];
        const int ekj = ikj[t];
        const int bin = bins[t];
        const float ae0 = aeL[bin * D_DIM + d0];
        const float ae1 = aeL[bin * D_DIM + d0 + 1];
        const int64_t kvb = (int64_t)ekj * 256;
        unsigned kw = *(const unsigned*)&KVh[kvb + d0];
        unsigned vw = *(const unsigned*)&KVh[kvb + 128 + d0];
        float k0, k1; bf2x(kw, k0, k1);
        float pd = (k0 + ae0) * (q0 + ae0) + (k1 + ae1) * (q1 + ae1);
        pd += __shfl_xor(pd, 1);
        pd += __shfl_xor(pd, 2);
        pd += __shfl_xor(pd, 4);
        const float ex = expf(pd * 0.25f + battn[ekj] * dw);
        den += ex;
        float v0, v1; bf2x(vw, v0, v1);
        acc0 += ex * (v0 + ae0);
        acc1 += ex * (v1 + ae1);
    }
    const float inv = (den > 0.f) ? 1.f / den : 0.f;
    const int64_t base = (int64_t)e * D_DIM;
    const float x0 = acc0 * inv + bond[base + d0];
    const float x1 = acc1 * inv + bond[base + d0 + 1];
    he[base + d0]     = x0;
    he[base + d0 + 1] = x1;
    float sum = x0 + x1;
    #pragma unroll
    for (int o = 32; o > 0; o >>= 1) sum += __shfl_xor(sum, o);
    const float mean = sum * (1.f / 128.f);
    const float dx0 = x0 - mean, dx1 = x1 - mean;
    float var = dx0 * dx0 + dx1 * dx1;
    #pragma unroll
    for (int o = 32; o > 0; o >>= 1) var += __shfl_xor(var, o);
    const float rs = rsqrtf(var * (1.f / 128.f) + 1e-5f);
    const float h0v = dx0 * rs * g1[d0]     + b1[d0];
    const float h1v = dx1 * rs * g1[d0 + 1] + b1[d0 + 1];
    *(unsigned*)&hbf[base + d0] =
        (unsigned)f2bf(h0v) | ((unsigned)f2bf(h1v) << 16);
}

// ---------------------------------------------------------------------------
// FUSED FFN (GEMM1 -> LDS -> GEMM2) + residual + LN2 -> d_out.
// he is PREFETCHED into registers at kernel entry; its global-load latency
// resolves under the 128 MFMA ops of GEMM1+GEMM2 (R20's 298us was a
// latency-bound epilogue: 16 serial iterations x 2 dependent he loads).
// ---------------------------------------------------------------------------
__launch_bounds__(256)
__global__ void ffn_fused(const unsigned short* __restrict__ hbf,
                          const unsigned short* __restrict__ W1t,
                          const unsigned short* __restrict__ W2t,
                          const float* __restrict__ he,
                          const float* __restrict__ g2, const float* __restrict__ b2,
                          float* __restrict__ outp)
{
    __shared__ __align__(16) unsigned char lds[64 * 264 * 2];   // 33,792 B
    unsigned short* ms = (unsigned short*)lds;                  // [64][264] bf16
    float (*cs)[132] = (float(*)[132])lds;                      // [64][132] f32
    const int lane = threadIdx.x & 63, w = threadIdx.x >> 6;
    const int m0 = blockIdx.x * 64 + w * 16;
    const int lr = lane & 15, g = lane >> 4;

    // ---- prefetch he (independent loads; resolve under the MFMA work) ----
    float hev0[16], hev1[16];
    #pragma unroll
    for (int i = 0; i < 16; ++i) {
        const int64_t rg = (int64_t)(m0 + i) * 128;
        hev0[i] = he[rg + lane];
        hev1[i] = he[rg + 64 + lane];
    }

    // ---- GEMM1: mid = relu(h @ W1), 16 n-tiles, K=128 ----
    {
        f32x4 acc[16];
        #pragma unroll
        for (int n = 0; n < 16; ++n) acc[n] = (f32x4){0.f, 0.f, 0.f, 0.f};
        #pragma unroll
        for (int kk = 0; kk < 4; ++kk) {
            const bf16x8 a = *(const bf16x8*)&hbf[(int64_t)(m0 + lr) * 128 + kk * 32 + g * 8];
            #pragma unroll
            for (int n = 0; n < 16; ++n) {
                const bf16x8 b = *(const bf16x8*)&W1t[(n * 16 + lr) * 128 + kk * 32 + g * 8];
                acc[n] = __builtin_amdgcn_mfma_f32_16x16x32_bf16(a, b, acc[n], 0, 0, 0);
            }
        }
        #pragma unroll
        for (int n = 0; n < 16; ++n)
            #pragma unroll
            for (int r = 0; r < 4; ++r) {
                float v = acc[n][r];
                v = v > 0.f ? v : 0.f;
                ms[(w * 16 + g * 4 + r) * 264 + n * 16 + lr] = f2bf(v);
            }
    }
    __syncthreads();

    // ---- GEMM2: C = mid @ W2, 8 n-tiles, K=256 ----
    f32x4 acc2[8];
    #pragma unroll
    for (int n = 0; n < 8; ++n) acc2[n] = (f32x4){0.f, 0.f, 0.f, 0.f};
    #pragma unroll
    for (int kk = 0; kk < 8; ++kk) {
        const bf16x8 a = *(const bf16x8*)&ms[(w * 16 + lr) * 264 + kk * 32 + g * 8];
        #pragma unroll
        for (int n = 0; n < 8; ++n) {
            const bf16x8 b = *(const bf16x8*)&W2t[(n * 16 + lr) * 256 + kk * 32 + g * 8];
            acc2[n] = __builtin_amdgcn_mfma_f32_16x16x32_bf16(a, b, acc2[n], 0, 0, 0);
        }
    }
    __syncthreads();   // all ms reads done before cs overwrites the region
    #pragma unroll
    for (int n = 0; n < 8; ++n)
        #pragma unroll
        for (int r = 0; r < 4; ++r)
            cs[w * 16 + g * 4 + r][n * 16 + lr] = acc2[n][r];
    __syncthreads();

    // ---- residual + LN2 on the wave's own 16 rows (registers only) ----
    #pragma unroll 2
    for (int i = 0; i < 16; ++i) {
        const int row = w * 16 + i;
        const int64_t rg = (int64_t)(blockIdx.x * 64 + row) * 128;
        float x0 = cs[row][lane]      + hev0[i];
        float x1 = cs[row][64 + lane] + hev1[i];
        float s = x0 + x1;
        #pragma unroll
        for (int o = 32; o > 0; o >>= 1) s += __shfl_xor(s, o);
        const float mean = s * (1.f / 128.f);
        const float d0 = x0 - mean, d1 = x1 - mean;
        float v = d0 * d0 + d1 * d1;
        #pragma unroll
        for (int o = 32; o > 0; o >>= 1) v += __shfl_xor(v, o);
        const float rs = rsqrtf(v * (1.f / 128.f) + 1e-5f);
        outp[rg + lane]      = d0 * rs * g2[lane]      + b2[lane];
        outp[rg + 64 + lane] = d1 * rs * g2[lane + 64] + b2[lane + 64];
    }
}

// ---------------------------------------------------------------------------
extern "C" void kernel_launch(void* const* d_in, const int* in_sizes, int n_in,
                              void* d_out, int out_size, void* d_ws, size_t ws_size,
                              hipStream_t stream)
{
    const float* bond     = (const float*)d_in[0];
    const float* pos      = (const float*)d_in[1];
    const float* battn    = (const float*)d_in[2];
    const float* ang_tab  = (const float*)d_in[3];
    const float* ang_in_W = (const float*)d_in[4];
    const float* ang_in_b = (const float*)d_in[5];
    const float* ang2_W   = (const float*)d_in[6];
    const float* ang2_b   = (const float*)d_in[7];
    const float* ang1_W   = (const float*)d_in[8];
    const float* ang1_b   = (const float*)d_in[9];
    const float* k_W      = (const float*)d_in[10];
    const float* q_W      = (const float*)d_in[11];
    const float* v_W      = (const float*)d_in[12];
    const float* dis_W    = (const float*)d_in[13];
    const float* ffn_W1   = (const float*)d_in[14];
    const float* ffn_W2   = (const float*)d_in[15];
    const float* ln1_g    = (const float*)d_in[16];
    const float* ln1_b    = (const float*)d_in[17];
    const float* ln2_g    = (const float*)d_in[18];
    const float* ln2_b    = (const float*)d_in[19];
    const int*   index_kj = (const int*)d_in[20];
    const int*   index_ji = (const int*)d_in[21];
    const int*   idx_i    = (const int*)d_in[22];
    const int*   idx_j    = (const int*)d_in[23];
    const int*   idx_k    = (const int*)d_in[24];

    float* ws = (float*)d_ws;
    // ws layout (float offsets) — ~211 MB, no overlaps
    int*            bins  = (int*)(ws + 0);          //   400,000
    int*            slot  = (int*)(ws + 400000);     //   400,000
    int*            offs  = (int*)(ws + 800000);     //   200,000
    int*            cnt   = (int*)(ws + 1000000);    //   200,000
    int*            cur   = (int*)(ws + 1200000);    //   200,000 (contiguous w/ cnt)
    int*            bsum  = (int*)(ws + 1400000);    //     1,024
    float*          aeT   = ws + 1401088;            //       768
    unsigned short* W1t   = (unsigned short*)(ws + 1401856);   // 32,768 us
    unsigned short* W2t   = (unsigned short*)(ws + 1418240);   // 32,768 us
    unsigned short* Wt    = (unsigned short*)(ws + 1434624);   // 49,152 us
    float*          heb   = ws + 1459200;            // 25,600,000
    unsigned short* hbf   = (unsigned short*)(ws + 27059200); // 25.6M us
    unsigned short* Qh    = (unsigned short*)(ws + 39859200); // 25.6M us

    // d_out holds KVh (E x 256 bf16 = exactly out bytes), then final out
    unsigned short* KVh = (unsigned short*)d_out;
    float*          out = (float*)d_out;

    hipMemsetAsync(cnt, 0, (size_t)2 * E_EDGES * sizeof(int), stream);  // cnt+cur

    ang_mlp_kernel<<<1, 256, 0, stream>>>(ang_tab, ang_in_W, ang_in_b,
                                          ang2_W, ang2_b, ang1_W, ang1_b, aeT);
    conv_w_kernel<<<192, 256, 0, stream>>>(k_W, q_W, v_W, ffn_W1, ffn_W2, Wt, W1t, W2t);
    tri_bins_kernel<<<(T_TRI + 255) / 256, 256, 0, stream>>>(
        pos, idx_i, idx_j, idx_k, index_ji, bins, cnt);

    const int NB = (E_EDGES + 255) / 256;    // 782
    scan1_kernel<<<NB, 256, 0, stream>>>(cnt, offs, bsum);
    scan2_kernel<<<1, 1024, 0, stream>>>(bsum, NB);
    scan3_kernel<<<NB, 256, 0, stream>>>(offs, bsum);
    fill_kernel<<<(T_TRI + 255) / 256, 256, 0, stream>>>(index_ji, offs, cur, slot);

    proj_mfma<<<E_EDGES / 64, 256, 0, stream>>>(bond, Wt, KVh, Qh);

    edge_att_kernel<<<E_EDGES / 4, 256, 0, stream>>>(
        KVh, Qh, aeT, bins, index_kj, slot, offs, cnt,
        battn, dis_W, bond, ln1_g, ln1_b, heb, hbf);

    ffn_fused<<<E_EDGES / 64, 256, 0, stream>>>(hbf, W1t, W2t, heb, ln2_g, ln2_b, out);
}

// Round 22
// 644.509 us; speedup vs baseline: 1.2284x; 1.1657x over previous
//
#include <hip/hip_runtime.h>
#include <cstdint>
#include <math.h>

// Problem constants (match reference)
#define N_ATOMS 30000
#define E_EDGES 200000
#define T_TRI   400000
#define D_DIM   128
#define H_HEADS 8
#define F_FEAT  16
#define CLS     6

typedef __attribute__((ext_vector_type(8))) short bf16x8;
typedef __attribute__((ext_vector_type(4))) float f32x4;

// bf16 helpers (RNE pack, bit-shift unpack)
static __device__ __forceinline__ unsigned short f2bf(float f) {
    union { float f; unsigned u; } v; v.f = f;
    unsigned r = v.u + 0x7FFFu + ((v.u >> 16) & 1u);
    return (unsigned short)(r >> 16);
}
static __device__ __forceinline__ void bf2x(unsigned u, float& a, float& b) {
    union { unsigned u; float f; } x, y;
    x.u = u << 16; y.u = u & 0xFFFF0000u;
    a = x.f; b = y.f;
}

// ---------------------------------------------------------------------------
// Kernel 1: 6-row angle MLP -> ae_table[6][128]
// ---------------------------------------------------------------------------
__launch_bounds__(256)
__global__ void ang_mlp_kernel(const float* __restrict__ tab,
                               const float* __restrict__ W0, const float* __restrict__ b0,
                               const float* __restrict__ W1, const float* __restrict__ b1,
                               const float* __restrict__ W2, const float* __restrict__ b2,
                               float* __restrict__ out)
{
    __shared__ float bufA[CLS * D_DIM];
    __shared__ float bufB[CLS * D_DIM];
    __shared__ float Wl[D_DIM * D_DIM];
    const int tid = threadIdx.x;
    for (int i = tid; i < CLS * D_DIM; i += 256) bufA[i] = tab[i];
    const float* Ws[3] = {W0, W1, W2};
    const float* bs[3] = {b0, b1, b2};
    float* in  = bufA;
    float* ob  = bufB;
    for (int l = 0; l < 3; ++l) {
        __syncthreads();
        for (int i = tid * 4; i < D_DIM * D_DIM; i += 256 * 4)
            *(float4*)&Wl[i] = *(const float4*)&Ws[l][i];
        __syncthreads();
        for (int o = tid; o < CLS * D_DIM; o += 256) {
            const int r = o >> 7, c = o & 127;
            float acc = bs[l][c];
            #pragma unroll 8
            for (int k = 0; k < D_DIM; ++k) acc += in[r * D_DIM + k] * Wl[k * D_DIM + c];
            ob[o] = fmaxf(acc, 0.f);
        }
        float* t = in; in = ob; ob = t;
    }
    __syncthreads();
    for (int i = tid; i < CLS * D_DIM; i += 256) out[i] = in[i];
}

// ---------------------------------------------------------------------------
// Kernel 2: bins (with atan2(+0,-0) degenerate-sign fix) + per-edge count.
// ---------------------------------------------------------------------------
__launch_bounds__(256)
__global__ void tri_bins_kernel(const float* __restrict__ pos,
                                const int* __restrict__ idx_i,
                                const int* __restrict__ idx_j,
                                const int* __restrict__ idx_k,
                                const int* __restrict__ iji,
                                int* __restrict__ bins,
                                int* __restrict__ cnt)
{
    const int t = blockIdx.x * 256 + threadIdx.x;
    if (t >= T_TRI) return;
    const int ii = idx_i[t], jj = idx_j[t], kk = idx_k[t];
    const float pix = pos[3*ii], piy = pos[3*ii+1], piz = pos[3*ii+2];
    const float jx = __fsub_rn(pos[3*jj],   pix);
    const float jy = __fsub_rn(pos[3*jj+1], piy);
    const float jz = __fsub_rn(pos[3*jj+2], piz);
    const float kx = __fsub_rn(pos[3*kk],   pix);
    const float ky = __fsub_rn(pos[3*kk+1], piy);
    const float kz = __fsub_rn(pos[3*kk+2], piz);
    const float a  = __fadd_rn(__fadd_rn(__fmul_rn(jx,kx), __fmul_rn(jy,ky)),
                               __fmul_rn(jz,kz));
    const float cx = __fsub_rn(__fmul_rn(jy,kz), __fmul_rn(jz,ky));
    const float cy = __fsub_rn(__fmul_rn(jz,kx), __fmul_rn(jx,kz));
    const float cz = __fsub_rn(__fmul_rn(jx,ky), __fmul_rn(jy,kx));
    const float ss = __fadd_rn(__fadd_rn(__fmul_rn(cx,cx), __fmul_rn(cy,cy)),
                               __fmul_rn(cz,cz));
    const float b  = __fsqrt_rn(ss);

    int bin;
    if (b == 0.0f && __float_as_uint(a) == 0x80000000u) {
        bin = 0;   // atan2(+0,-0): IEEE pi (bin 5) vs reference SVML 0 (bin 0)
    } else {
        const float angle = (float)atan2((double)b, (double)a);
        const float c = (float)(3.1415926 / 6.0);
        const float q = __fdiv_rn(angle, c);
        bin = (int)q;
        bin = bin < 0 ? 0 : (bin > CLS - 1 ? CLS - 1 : bin);
    }
    bins[t] = bin;
    atomicAdd(&cnt[iji[t]], 1);
}

// ---------------------------------------------------------------------------
// CSR build: block-scan (3 kernels) + scatter fill
// ---------------------------------------------------------------------------
__launch_bounds__(256)
__global__ void scan1_kernel(const int* __restrict__ cnt, int* __restrict__ offs,
                             int* __restrict__ bsum)
{
    __shared__ int buf[256];
    const int i = blockIdx.x * 256 + threadIdx.x;
    const int v = (i < E_EDGES) ? cnt[i] : 0;
    buf[threadIdx.x] = v;
    __syncthreads();
    for (int o = 1; o < 256; o <<= 1) {
        const int t = (threadIdx.x >= o) ? buf[threadIdx.x - o] : 0;
        __syncthreads();
        buf[threadIdx.x] += t;
        __syncthreads();
    }
    if (i < E_EDGES) offs[i] = buf[threadIdx.x] - v;
    if (threadIdx.x == 255) bsum[blockIdx.x] = buf[255];
}

__launch_bounds__(1024)
__global__ void scan2_kernel(int* __restrict__ bsum, int nb)
{
    __shared__ int buf[1024];
    const int tid = threadIdx.x;
    const int v = (tid < nb) ? bsum[tid] : 0;
    buf[tid] = v;
    __syncthreads();
    for (int o = 1; o < 1024; o <<= 1) {
        const int t = (tid >= o) ? buf[tid - o] : 0;
        __syncthreads();
        buf[tid] += t;
        __syncthreads();
    }
    if (tid < nb) bsum[tid] = buf[tid] - v;   // exclusive
}

__launch_bounds__(256)
__global__ void scan3_kernel(int* __restrict__ offs, const int* __restrict__ bsum)
{
    const int i = blockIdx.x * 256 + threadIdx.x;
    if (i < E_EDGES) offs[i] += bsum[blockIdx.x];
}

__launch_bounds__(256)
__global__ void fill_kernel(const int* __restrict__ iji, const int* __restrict__ offs,
                            int* __restrict__ cur, int* __restrict__ slot)
{
    const int t = blockIdx.x * 256 + threadIdx.x;
    if (t >= T_TRI) return;
    const int e = iji[t];
    const int p = offs[e] + atomicAdd(&cur[e], 1);
    slot[p] = t;
}

// ---------------------------------------------------------------------------
// Weight convert: Wt[384][128] = [kW|qW|vW]^T bf16;  W1t[256][128], W2t[128][256]
// ---------------------------------------------------------------------------
__launch_bounds__(256)
__global__ void conv_w_kernel(const float* __restrict__ kW, const float* __restrict__ qW,
                              const float* __restrict__ vW,
                              const float* __restrict__ W1, const float* __restrict__ W2,
                              unsigned short* __restrict__ Wt,
                              unsigned short* __restrict__ W1t,
                              unsigned short* __restrict__ W2t)
{
    const int i = blockIdx.x * 256 + threadIdx.x;
    if (i < 384 * 128) {               // Wt[n][k]
        const int n = i >> 7, k = i & 127;
        const int sel = n >> 7, c = n & 127;
        const float* W = (sel == 0) ? kW : (sel == 1) ? qW : vW;
        Wt[i] = f2bf(W[k * 128 + c]);
    }
    if (i < 128 * 256) {
        { const int n = i >> 7, k = i & 127;  W1t[n * 128 + k] = f2bf(W1[k * 256 + n]); }
        { const int n = i >> 8, k = i & 255;  W2t[n * 256 + k] = f2bf(W2[k * 128 + n]); }
    }
}

// ---------------------------------------------------------------------------
// Fused K/Q/V projection (MFMA), inline f32->bf16 A conversion.
// Output: KVh[E][256] (K cols 0-127, V cols 128-255), Qh[E][128].
// ---------------------------------------------------------------------------
__launch_bounds__(256)
__global__ void proj_mfma(const float* __restrict__ bond,
                          const unsigned short* __restrict__ Wt,
                          unsigned short* __restrict__ KVh,
                          unsigned short* __restrict__ Qh)
{
    __shared__ unsigned short ms[64 * 392];   // pitch 392 breaks bank alias
    const int lane = threadIdx.x & 63, w = threadIdx.x >> 6;
    const int m0 = blockIdx.x * 64 + w * 16;
    const int lr = lane & 15, g = lane >> 4;
    f32x4 acc[24];
    #pragma unroll
    for (int n = 0; n < 24; ++n) acc[n] = (f32x4){0.f, 0.f, 0.f, 0.f};
    #pragma unroll
    for (int kk = 0; kk < 4; ++kk) {
        const int64_t ab = (int64_t)(m0 + lr) * 128 + kk * 32 + g * 8;
        const float4 f0 = *(const float4*)&bond[ab];
        const float4 f1 = *(const float4*)&bond[ab + 4];
        bf16x8 a;
        a[0] = (short)f2bf(f0.x); a[1] = (short)f2bf(f0.y);
        a[2] = (short)f2bf(f0.z); a[3] = (short)f2bf(f0.w);
        a[4] = (short)f2bf(f1.x); a[5] = (short)f2bf(f1.y);
        a[6] = (short)f2bf(f1.z); a[7] = (short)f2bf(f1.w);
        #pragma unroll
        for (int n = 0; n < 24; ++n) {
            const bf16x8 b = *(const bf16x8*)&Wt[(n * 16 + lr) * 128 + kk * 32 + g * 8];
            acc[n] = __builtin_amdgcn_mfma_f32_16x16x32_bf16(a, b, acc[n], 0, 0, 0);
        }
    }
    #pragma unroll
    for (int n = 0; n < 24; ++n)
        #pragma unroll
        for (int r = 0; r < 4; ++r)
            ms[(w * 16 + g * 4 + r) * 392 + n * 16 + lr] = f2bf(acc[n][r]);
    __syncthreads();
    // cols 0-127 = K -> KV[0..127]; 128-255 = Q -> Q; 256-383 = V -> KV[128..255]
    for (int idx = threadIdx.x; idx < 64 * 48; idx += 256) {
        const int row = idx / 48, c8 = (idx % 48) * 8;
        const int e = blockIdx.x * 64 + row;
        const uint4 v = *(const uint4*)&ms[row * 392 + c8];
        if (c8 < 128)       *(uint4*)&KVh[(int64_t)e * 256 + c8] = v;
        else if (c8 < 256)  *(uint4*)&Qh[(int64_t)e * 128 + (c8 - 128)] = v;
        else                *(uint4*)&KVh[(int64_t)e * 256 + 128 + (c8 - 256)] = v;
    }
}

// ---------------------------------------------------------------------------
// FUSED per-edge attention + aggregation + he + LN1 (-> bf16 h).
// K,V packed per-row in KVh for gather locality.
// ---------------------------------------------------------------------------
__launch_bounds__(256)
__global__ void edge_att_kernel(const unsigned short* __restrict__ KVh,
                                const unsigned short* __restrict__ Qh,
                                const float* __restrict__ aeT,
                                const int* __restrict__ bins,
                                const int* __restrict__ ikj,
                                const int* __restrict__ slot,
                                const int* __restrict__ offs,
                                const int* __restrict__ cnt,
                                const float* __restrict__ battn,
                                const float* __restrict__ disW,
                                const float* __restrict__ bond,
                                const float* __restrict__ g1,
                                const float* __restrict__ b1,
                                float* __restrict__ he,
                                unsigned short* __restrict__ hbf)
{
    __shared__ float aeL[CLS * D_DIM];
    for (int i = threadIdx.x; i < CLS * D_DIM; i += 256) aeL[i] = aeT[i];
    __syncthreads();
    const int wid  = threadIdx.x >> 6;
    const int lane = threadIdx.x & 63;
    const int e = blockIdx.x * 4 + wid;
    const int d0 = lane * 2;
    const int h  = lane >> 3;
    const float dw = disW[h];

    unsigned qw = *(const unsigned*)&Qh[(int64_t)e * D_DIM + d0];
    float q0, q1; bf2x(qw, q0, q1);

    float acc0 = 0.f, acc1 = 0.f, den = 0.f;
    const int start = offs[e], n = cnt[e];
    for (int s = 0; s < n; ++s) {
        const int t   = slot[start + s];
        const int ekj = ikj[t];
        const int bin = bins[t];
        const float ae0 = aeL[bin * D_DIM + d0];
        const float ae1 = aeL[bin * D_DIM + d0 + 1];
        const int64_t kvb = (int64_t)ekj * 256;
        unsigned kw = *(const unsigned*)&KVh[kvb + d0];
        unsigned vw = *(const unsigned*)&KVh[kvb + 128 + d0];
        float k0, k1; bf2x(kw, k0, k1);
        float pd = (k0 + ae0) * (q0 + ae0) + (k1 + ae1) * (q1 + ae1);
        pd += __shfl_xor(pd, 1);
        pd += __shfl_xor(pd, 2);
        pd += __shfl_xor(pd, 4);
        const float ex = expf(pd * 0.25f + battn[ekj] * dw);
        den += ex;
        float v0, v1; bf2x(vw, v0, v1);
        acc0 += ex * (v0 + ae0);
        acc1 += ex * (v1 + ae1);
    }
    const float inv = (den > 0.f) ? 1.f / den : 0.f;
    const int64_t base = (int64_t)e * D_DIM;
    const float x0 = acc0 * inv + bond[base + d0];
    const float x1 = acc1 * inv + bond[base + d0 + 1];
    he[base + d0]     = x0;
    he[base + d0 + 1] = x1;
    float sum = x0 + x1;
    #pragma unroll
    for (int o = 32; o > 0; o >>= 1) sum += __shfl_xor(sum, o);
    const float mean = sum * (1.f / 128.f);
    const float dx0 = x0 - mean, dx1 = x1 - mean;
    float var = dx0 * dx0 + dx1 * dx1;
    #pragma unroll
    for (int o = 32; o > 0; o >>= 1) var += __shfl_xor(var, o);
    const float rs = rsqrtf(var * (1.f / 128.f) + 1e-5f);
    const float h0v = dx0 * rs * g1[d0]     + b1[d0];
    const float h1v = dx1 * rs * g1[d0 + 1] + b1[d0 + 1];
    *(unsigned*)&hbf[base + d0] =
        (unsigned)f2bf(h0v) | ((unsigned)f2bf(h1v) << 16);
}

// ---------------------------------------------------------------------------
// FUSED FFN (GEMM1 -> LDS -> GEMM2) + residual + LN2 -> d_out.
// B-REUSE layout: each wave owns ALL 64 rows x (N/4) columns, so every
// B-fragment load feeds 4 MFMAs and each kk-step has 16 independent MFMAs
// (R21 was latency-bound: 128 B-loads/wave with zero reuse).
// he prefetched into registers at entry (resolves under the MFMA work).
// ---------------------------------------------------------------------------
__launch_bounds__(256)
__global__ void ffn_fused(const unsigned short* __restrict__ hbf,
                          const unsigned short* __restrict__ W1t,
                          const unsigned short* __restrict__ W2t,
                          const float* __restrict__ he,
                          const float* __restrict__ g2, const float* __restrict__ b2,
                          float* __restrict__ outp)
{
    __shared__ __align__(16) unsigned char lds[64 * 264 * 2];   // 33,792 B
    unsigned short* ms = (unsigned short*)lds;                  // [64][264] bf16
    float (*cs)[132] = (float(*)[132])lds;                      // [64][132] f32
    const int lane = threadIdx.x & 63, w = threadIdx.x >> 6;
    const int base_row = blockIdx.x * 64;
    const int lr = lane & 15, g = lane >> 4;

    // ---- prefetch he for the epilogue (wave's 16 rows) ----
    float hev0[16], hev1[16];
    #pragma unroll
    for (int i = 0; i < 16; ++i) {
        const int64_t rg = (int64_t)(base_row + w * 16 + i) * 128;
        hev0[i] = he[rg + lane];
        hev1[i] = he[rg + 64 + lane];
    }

    // ---- GEMM1: wave w -> cols [w*64, w*64+64), all 64 rows; K=128 ----
    {
        f32x4 acc[4][4];
        #pragma unroll
        for (int m = 0; m < 4; ++m)
            #pragma unroll
            for (int n = 0; n < 4; ++n) acc[m][n] = (f32x4){0.f, 0.f, 0.f, 0.f};
        #pragma unroll
        for (int kk = 0; kk < 4; ++kk) {
            bf16x8 a[4], b[4];
            #pragma unroll
            for (int m = 0; m < 4; ++m)
                a[m] = *(const bf16x8*)&hbf[(int64_t)(base_row + m * 16 + lr) * 128 + kk * 32 + g * 8];
            #pragma unroll
            for (int n = 0; n < 4; ++n)
                b[n] = *(const bf16x8*)&W1t[((w * 4 + n) * 16 + lr) * 128 + kk * 32 + g * 8];
            #pragma unroll
            for (int m = 0; m < 4; ++m)
                #pragma unroll
                for (int n = 0; n < 4; ++n)
                    acc[m][n] = __builtin_amdgcn_mfma_f32_16x16x32_bf16(a[m], b[n], acc[m][n], 0, 0, 0);
        }
        #pragma unroll
        for (int m = 0; m < 4; ++m)
            #pragma unroll
            for (int n = 0; n < 4; ++n)
                #pragma unroll
                for (int r = 0; r < 4; ++r) {
                    float v = acc[m][n][r];
                    v = v > 0.f ? v : 0.f;
                    ms[(m * 16 + g * 4 + r) * 264 + (w * 4 + n) * 16 + lr] = f2bf(v);
                }
    }
    __syncthreads();

    // ---- GEMM2: wave w -> cols [w*32, w*32+32), all 64 rows; K=256 ----
    f32x4 acc2[4][2];
    #pragma unroll
    for (int m = 0; m < 4; ++m)
        #pragma unroll
        for (int n = 0; n < 2; ++n) acc2[m][n] = (f32x4){0.f, 0.f, 0.f, 0.f};
    #pragma unroll
    for (int kk = 0; kk < 8; ++kk) {
        bf16x8 a[4], b[2];
        #pragma unroll
        for (int m = 0; m < 4; ++m)
            a[m] = *(const bf16x8*)&ms[(m * 16 + lr) * 264 + kk * 32 + g * 8];
        #pragma unroll
        for (int n = 0; n < 2; ++n)
            b[n] = *(const bf16x8*)&W2t[((w * 2 + n) * 16 + lr) * 256 + kk * 32 + g * 8];
        #pragma unroll
        for (int m = 0; m < 4; ++m)
            #pragma unroll
            for (int n = 0; n < 2; ++n)
                acc2[m][n] = __builtin_amdgcn_mfma_f32_16x16x32_bf16(a[m], b[n], acc2[m][n], 0, 0, 0);
    }
    __syncthreads();   // all ms reads done before cs overwrites the region
    #pragma unroll
    for (int m = 0; m < 4; ++m)
        #pragma unroll
        for (int n = 0; n < 2; ++n)
            #pragma unroll
            for (int r = 0; r < 4; ++r)
                cs[m * 16 + g * 4 + r][w * 32 + n * 16 + lr] = acc2[m][n][r];
    __syncthreads();

    // ---- residual + LN2 on the wave's own 16 rows (registers only) ----
    #pragma unroll 2
    for (int i = 0; i < 16; ++i) {
        const int row = w * 16 + i;
        const int64_t rg = (int64_t)(base_row + row) * 128;
        float x0 = cs[row][lane]      + hev0[i];
        float x1 = cs[row][64 + lane] + hev1[i];
        float s = x0 + x1;
        #pragma unroll
        for (int o = 32; o > 0; o >>= 1) s += __shfl_xor(s, o);
        const float mean = s * (1.f / 128.f);
        const float d0 = x0 - mean, d1 = x1 - mean;
        float v = d0 * d0 + d1 * d1;
        #pragma unroll
        for (int o = 32; o > 0; o >>= 1) v += __shfl_xor(v, o);
        const float rs = rsqrtf(v * (1.f / 128.f) + 1e-5f);
        outp[rg + lane]      = d0 * rs * g2[lane]      + b2[lane];
        outp[rg + 64 + lane] = d1 * rs * g2[lane + 64] + b2[lane + 64];
    }
}

// ---------------------------------------------------------------------------
extern "C" void kernel_launch(void* const* d_in, const int* in_sizes, int n_in,
                              void* d_out, int out_size, void* d_ws, size_t ws_size,
                              hipStream_t stream)
{
    const float* bond     = (const float*)d_in[0];
    const float* pos      = (const float*)d_in[1];
    const float* battn    = (const float*)d_in[2];
    const float* ang_tab  = (const float*)d_in[3];
    const float* ang_in_W = (const float*)d_in[4];
    const float* ang_in_b = (const float*)d_in[5];
    const float* ang2_W   = (const float*)d_in[6];
    const float* ang2_b   = (const float*)d_in[7];
    const float* ang1_W   = (const float*)d_in[8];
    const float* ang1_b   = (const float*)d_in[9];
    const float* k_W      = (const float*)d_in[10];
    const float* q_W      = (const float*)d_in[11];
    const float* v_W      = (const float*)d_in[12];
    const float* dis_W    = (const float*)d_in[13];
    const float* ffn_W1   = (const float*)d_in[14];
    const float* ffn_W2   = (const float*)d_in[15];
    const float* ln1_g    = (const float*)d_in[16];
    const float* ln1_b    = (const float*)d_in[17];
    const float* ln2_g    = (const float*)d_in[18];
    const float* ln2_b    = (const float*)d_in[19];
    const int*   index_kj = (const int*)d_in[20];
    const int*   index_ji = (const int*)d_in[21];
    const int*   idx_i    = (const int*)d_in[22];
    const int*   idx_j    = (const int*)d_in[23];
    const int*   idx_k    = (const int*)d_in[24];

    float* ws = (float*)d_ws;
    // ws layout (float offsets) — ~211 MB, no overlaps
    int*            bins  = (int*)(ws + 0);          //   400,000
    int*            slot  = (int*)(ws + 400000);     //   400,000
    int*            offs  = (int*)(ws + 800000);     //   200,000
    int*            cnt   = (int*)(ws + 1000000);    //   200,000
    int*            cur   = (int*)(ws + 1200000);    //   200,000 (contiguous w/ cnt)
    int*            bsum  = (int*)(ws + 1400000);    //     1,024
    float*          aeT   = ws + 1401088;            //       768
    unsigned short* W1t   = (unsigned short*)(ws + 1401856);   // 32,768 us
    unsigned short* W2t   = (unsigned short*)(ws + 1418240);   // 32,768 us
    unsigned short* Wt    = (unsigned short*)(ws + 1434624);   // 49,152 us
    float*          heb   = ws + 1459200;            // 25,600,000
    unsigned short* hbf   = (unsigned short*)(ws + 27059200); // 25.6M us
    unsigned short* Qh    = (unsigned short*)(ws + 39859200); // 25.6M us

    // d_out holds KVh (E x 256 bf16 = exactly out bytes), then final out
    unsigned short* KVh = (unsigned short*)d_out;
    float*          out = (float*)d_out;

    hipMemsetAsync(cnt, 0, (size_t)2 * E_EDGES * sizeof(int), stream);  // cnt+cur

    ang_mlp_kernel<<<1, 256, 0, stream>>>(ang_tab, ang_in_W, ang_in_b,
                                          ang2_W, ang2_b, ang1_W, ang1_b, aeT);
    conv_w_kernel<<<192, 256, 0, stream>>>(k_W, q_W, v_W, ffn_W1, ffn_W2, Wt, W1t, W2t);
    tri_bins_kernel<<<(T_TRI + 255) / 256, 256, 0, stream>>>(
        pos, idx_i, idx_j, idx_k, index_ji, bins, cnt);

    const int NB = (E_EDGES + 255) / 256;    // 782
    scan1_kernel<<<NB, 256, 0, stream>>>(cnt, offs, bsum);
    scan2_kernel<<<1, 1024, 0, stream>>>(bsum, NB);
    scan3_kernel<<<NB, 256, 0, stream>>>(offs, bsum);
    fill_kernel<<<(T_TRI + 255) / 256, 256, 0, stream>>>(index_ji, offs, cur, slot);

    proj_mfma<<<E_EDGES / 64, 256, 0, stream>>>(bond, Wt, KVh, Qh);

    edge_att_kernel<<<E_EDGES / 4, 256, 0, stream>>>(
        KVh, Qh, aeT, bins, index_kj, slot, offs, cnt,
        battn, dis_W, bond, ln1_g, ln1_b, heb, hbf);

    ffn_fused<<<E_EDGES / 64, 256, 0, stream>>>(hbf, W1t, W2t, heb, ln2_g, ln2_b, out);
}

// Round 23
// 563.889 us; speedup vs baseline: 1.4040x; 1.1430x over previous
//
#include <hip/hip_runtime.h>
#include <cstdint>
#include <math.h>

// Problem constants (match reference)
#define N_ATOMS 30000
#define E_EDGES 200000
#define T_TRI   400000
#define D_DIM   128
#define H_HEADS 8
#define F_FEAT  16
#define CLS     6

typedef __attribute__((ext_vector_type(8))) short bf16x8;
typedef __attribute__((ext_vector_type(4))) float f32x4;

// bf16 helpers (RNE pack, bit-shift unpack)
static __device__ __forceinline__ unsigned short f2bf(float f) {
    union { float f; unsigned u; } v; v.f = f;
    unsigned r = v.u + 0x7FFFu + ((v.u >> 16) & 1u);
    return (unsigned short)(r >> 16);
}
static __device__ __forceinline__ void bf2x(unsigned u, float& a, float& b) {
    union { unsigned u; float f; } x, y;
    x.u = u << 16; y.u = u & 0xFFFF0000u;
    a = x.f; b = y.f;
}

// ---------------------------------------------------------------------------
// Kernel 1: 6-row angle MLP -> ae_table[6][128]
// ---------------------------------------------------------------------------
__launch_bounds__(256)
__global__ void ang_mlp_kernel(const float* __restrict__ tab,
                               const float* __restrict__ W0, const float* __restrict__ b0,
                               const float* __restrict__ W1, const float* __restrict__ b1,
                               const float* __restrict__ W2, const float* __restrict__ b2,
                               float* __restrict__ out)
{
    __shared__ float bufA[CLS * D_DIM];
    __shared__ float bufB[CLS * D_DIM];
    __shared__ float Wl[D_DIM * D_DIM];
    const int tid = threadIdx.x;
    for (int i = tid; i < CLS * D_DIM; i += 256) bufA[i] = tab[i];
    const float* Ws[3] = {W0, W1, W2};
    const float* bs[3] = {b0, b1, b2};
    float* in  = bufA;
    float* ob  = bufB;
    for (int l = 0; l < 3; ++l) {
        __syncthreads();
        for (int i = tid * 4; i < D_DIM * D_DIM; i += 256 * 4)
            *(float4*)&Wl[i] = *(const float4*)&Ws[l][i];
        __syncthreads();
        for (int o = tid; o < CLS * D_DIM; o += 256) {
            const int r = o >> 7, c = o & 127;
            float acc = bs[l][c];
            #pragma unroll 8
            for (int k = 0; k < D_DIM; ++k) acc += in[r * D_DIM + k] * Wl[k * D_DIM + c];
            ob[o] = fmaxf(acc, 0.f);
        }
        float* t = in; in = ob; ob = t;
    }
    __syncthreads();
    for (int i = tid; i < CLS * D_DIM; i += 256) out[i] = in[i];
}

// ---------------------------------------------------------------------------
// Kernel 2: bins (with atan2(+0,-0) degenerate-sign fix) + per-edge count.
// ---------------------------------------------------------------------------
__launch_bounds__(256)
__global__ void tri_bins_kernel(const float* __restrict__ pos,
                                const int* __restrict__ idx_i,
                                const int* __restrict__ idx_j,
                                const int* __restrict__ idx_k,
                                const int* __restrict__ iji,
                                int* __restrict__ bins,
                                int* __restrict__ cnt)
{
    const int t = blockIdx.x * 256 + threadIdx.x;
    if (t >= T_TRI) return;
    const int ii = idx_i[t], jj = idx_j[t], kk = idx_k[t];
    const float pix = pos[3*ii], piy = pos[3*ii+1], piz = pos[3*ii+2];
    const float jx = __fsub_rn(pos[3*jj],   pix);
    const float jy = __fsub_rn(pos[3*jj+1], piy);
    const float jz = __fsub_rn(pos[3*jj+2], piz);
    const float kx = __fsub_rn(pos[3*kk],   pix);
    const float ky = __fsub_rn(pos[3*kk+1], piy);
    const float kz = __fsub_rn(pos[3*kk+2], piz);
    const float a  = __fadd_rn(__fadd_rn(__fmul_rn(jx,kx), __fmul_rn(jy,ky)),
                               __fmul_rn(jz,kz));
    const float cx = __fsub_rn(__fmul_rn(jy,kz), __fmul_rn(jz,ky));
    const float cy = __fsub_rn(__fmul_rn(jz,kx), __fmul_rn(jx,kz));
    const float cz = __fsub_rn(__fmul_rn(jx,ky), __fmul_rn(jy,kx));
    const float ss = __fadd_rn(__fadd_rn(__fmul_rn(cx,cx), __fmul_rn(cy,cy)),
                               __fmul_rn(cz,cz));
    const float b  = __fsqrt_rn(ss);

    int bin;
    if (b == 0.0f && __float_as_uint(a) == 0x80000000u) {
        bin = 0;   // atan2(+0,-0): IEEE pi (bin 5) vs reference SVML 0 (bin 0)
    } else {
        const float angle = (float)atan2((double)b, (double)a);
        const float c = (float)(3.1415926 / 6.0);
        const float q = __fdiv_rn(angle, c);
        bin = (int)q;
        bin = bin < 0 ? 0 : (bin > CLS - 1 ? CLS - 1 : bin);
    }
    bins[t] = bin;
    atomicAdd(&cnt[iji[t]], 1);
}

// ---------------------------------------------------------------------------
// CSR build: block-scan (3 kernels) + scatter fill
// ---------------------------------------------------------------------------
__launch_bounds__(256)
__global__ void scan1_kernel(const int* __restrict__ cnt, int* __restrict__ offs,
                             int* __restrict__ bsum)
{
    __shared__ int buf[256];
    const int i = blockIdx.x * 256 + threadIdx.x;
    const int v = (i < E_EDGES) ? cnt[i] : 0;
    buf[threadIdx.x] = v;
    __syncthreads();
    for (int o = 1; o < 256; o <<= 1) {
        const int t = (threadIdx.x >= o) ? buf[threadIdx.x - o] : 0;
        __syncthreads();
        buf[threadIdx.x] += t;
        __syncthreads();
    }
    if (i < E_EDGES) offs[i] = buf[threadIdx.x] - v;
    if (threadIdx.x == 255) bsum[blockIdx.x] = buf[255];
}

__launch_bounds__(1024)
__global__ void scan2_kernel(int* __restrict__ bsum, int nb)
{
    __shared__ int buf[1024];
    const int tid = threadIdx.x;
    const int v = (tid < nb) ? bsum[tid] : 0;
    buf[tid] = v;
    __syncthreads();
    for (int o = 1; o < 1024; o <<= 1) {
        const int t = (tid >= o) ? buf[tid - o] : 0;
        __syncthreads();
        buf[tid] += t;
        __syncthreads();
    }
    if (tid < nb) bsum[tid] = buf[tid] - v;   // exclusive
}

__launch_bounds__(256)
__global__ void scan3_kernel(int* __restrict__ offs, const int* __restrict__ bsum)
{
    const int i = blockIdx.x * 256 + threadIdx.x;
    if (i < E_EDGES) offs[i] += bsum[blockIdx.x];
}

__launch_bounds__(256)
__global__ void fill_kernel(const int* __restrict__ iji, const int* __restrict__ offs,
                            int* __restrict__ cur, int* __restrict__ slot)
{
    const int t = blockIdx.x * 256 + threadIdx.x;
    if (t >= T_TRI) return;
    const int e = iji[t];
    const int p = offs[e] + atomicAdd(&cur[e], 1);
    slot[p] = t;
}

// ---------------------------------------------------------------------------
// Weight convert: Wt[384][128] = [kW|qW|vW]^T bf16;  W1t[256][128], W2t[128][256]
// ---------------------------------------------------------------------------
__launch_bounds__(256)
__global__ void conv_w_kernel(const float* __restrict__ kW, const float* __restrict__ qW,
                              const float* __restrict__ vW,
                              const float* __restrict__ W1, const float* __restrict__ W2,
                              unsigned short* __restrict__ Wt,
                              unsigned short* __restrict__ W1t,
                              unsigned short* __restrict__ W2t)
{
    const int i = blockIdx.x * 256 + threadIdx.x;
    if (i < 384 * 128) {               // Wt[n][k]
        const int n = i >> 7, k = i & 127;
        const int sel = n >> 7, c = n & 127;
        const float* W = (sel == 0) ? kW : (sel == 1) ? qW : vW;
        Wt[i] = f2bf(W[k * 128 + c]);
    }
    if (i < 128 * 256) {
        { const int n = i >> 7, k = i & 127;  W1t[n * 128 + k] = f2bf(W1[k * 256 + n]); }
        { const int n = i >> 8, k = i & 255;  W2t[n * 256 + k] = f2bf(W2[k * 128 + n]); }
    }
}

// ---------------------------------------------------------------------------
// Fused K/Q/V projection (MFMA) with B-REUSE: wave w owns ALL 64 rows x
// 6 n-tiles (cols [w*96, w*96+96)).  Per kk-step: 4 A-frags (inline
// f32->bf16) + 6 B-frags -> 24 independent MFMAs (was 1 B-load per MFMA,
// latency-bound at 219us / MfmaUtil 3.5%).
// Output: KVh[E][256] (K cols 0-127, V cols 128-255), Qh[E][128].
// ---------------------------------------------------------------------------
__launch_bounds__(256)
__global__ void proj_mfma(const float* __restrict__ bond,
                          const unsigned short* __restrict__ Wt,
                          unsigned short* __restrict__ KVh,
                          unsigned short* __restrict__ Qh)
{
    __shared__ unsigned short ms[64 * 392];   // pitch 392 breaks bank alias
    const int lane = threadIdx.x & 63, w = threadIdx.x >> 6;
    const int base_row = blockIdx.x * 64;
    const int lr = lane & 15, g = lane >> 4;
    f32x4 acc[4][6];
    #pragma unroll
    for (int m = 0; m < 4; ++m)
        #pragma unroll
        for (int n = 0; n < 6; ++n) acc[m][n] = (f32x4){0.f, 0.f, 0.f, 0.f};
    #pragma unroll
    for (int kk = 0; kk < 4; ++kk) {
        bf16x8 a[4], b[6];
        #pragma unroll
        for (int m = 0; m < 4; ++m) {
            const int64_t ab = (int64_t)(base_row + m * 16 + lr) * 128 + kk * 32 + g * 8;
            const float4 f0 = *(const float4*)&bond[ab];
            const float4 f1 = *(const float4*)&bond[ab + 4];
            a[m][0] = (short)f2bf(f0.x); a[m][1] = (short)f2bf(f0.y);
            a[m][2] = (short)f2bf(f0.z); a[m][3] = (short)f2bf(f0.w);
            a[m][4] = (short)f2bf(f1.x); a[m][5] = (short)f2bf(f1.y);
            a[m][6] = (short)f2bf(f1.z); a[m][7] = (short)f2bf(f1.w);
        }
        #pragma unroll
        for (int n = 0; n < 6; ++n)
            b[n] = *(const bf16x8*)&Wt[((w * 6 + n) * 16 + lr) * 128 + kk * 32 + g * 8];
        #pragma unroll
        for (int m = 0; m < 4; ++m)
            #pragma unroll
            for (int n = 0; n < 6; ++n)
                acc[m][n] = __builtin_amdgcn_mfma_f32_16x16x32_bf16(a[m], b[n], acc[m][n], 0, 0, 0);
    }
    #pragma unroll
    for (int m = 0; m < 4; ++m)
        #pragma unroll
        for (int n = 0; n < 6; ++n)
            #pragma unroll
            for (int r = 0; r < 4; ++r)
                ms[(m * 16 + g * 4 + r) * 392 + (w * 6 + n) * 16 + lr] = f2bf(acc[m][n][r]);
    __syncthreads();
    // cols 0-127 = K -> KV[0..127]; 128-255 = Q -> Q; 256-383 = V -> KV[128..255]
    for (int idx = threadIdx.x; idx < 64 * 48; idx += 256) {
        const int row = idx / 48, c8 = (idx % 48) * 8;
        const int e = base_row + row;
        const uint4 v = *(const uint4*)&ms[row * 392 + c8];
        if (c8 < 128)       *(uint4*)&KVh[(int64_t)e * 256 + c8] = v;
        else if (c8 < 256)  *(uint4*)&Qh[(int64_t)e * 128 + (c8 - 128)] = v;
        else                *(uint4*)&KVh[(int64_t)e * 256 + 128 + (c8 - 256)] = v;
    }
}

// ---------------------------------------------------------------------------
// FUSED per-edge attention + aggregation + he + LN1 (-> bf16 h).
// K,V packed per-row in KVh for gather locality.
// ---------------------------------------------------------------------------
__launch_bounds__(256)
__global__ void edge_att_kernel(const unsigned short* __restrict__ KVh,
                                const unsigned short* __restrict__ Qh,
                                const float* __restrict__ aeT,
                                const int* __restrict__ bins,
                                const int* __restrict__ ikj,
                                const int* __restrict__ slot,
                                const int* __restrict__ offs,
                                const int* __restrict__ cnt,
                                const float* __restrict__ battn,
                                const float* __restrict__ disW,
                                const float* __restrict__ bond,
                                const float* __restrict__ g1,
                                const float* __restrict__ b1,
                                float* __restrict__ he,
                                unsigned short* __restrict__ hbf)
{
    __shared__ float aeL[CLS * D_DIM];
    for (int i = threadIdx.x; i < CLS * D_DIM; i += 256) aeL[i] = aeT[i];
    __syncthreads();
    const int wid  = threadIdx.x >> 6;
    const int lane = threadIdx.x & 63;
    const int e = blockIdx.x * 4 + wid;
    const int d0 = lane * 2;
    const int h  = lane >> 3;
    const float dw = disW[h];

    unsigned qw = *(const unsigned*)&Qh[(int64_t)e * D_DIM + d0];
    float q0, q1; bf2x(qw, q0, q1);

    float acc0 = 0.f, acc1 = 0.f, den = 0.f;
    const int start = offs[e], n = cnt[e];
    for (int s = 0; s < n; ++s) {
        const int t   = slot[start + s];
        const int ekj = ikj[t];
        const int bin = bins[t];
        const float ae0 = aeL[bin * D_DIM + d0];
        const float ae1 = aeL[bin * D_DIM + d0 + 1];
        const int64_t kvb = (int64_t)ekj * 256;
        unsigned kw = *(const unsigned*)&KVh[kvb + d0];
        unsigned vw = *(const unsigned*)&KVh[kvb + 128 + d0];
        float k0, k1; bf2x(kw, k0, k1);
        float pd = (k0 + ae0) * (q0 + ae0) + (k1 + ae1) * (q1 + ae1);
        pd += __shfl_xor(pd, 1);
        pd += __shfl_xor(pd, 2);
        pd += __shfl_xor(pd, 4);
        const float ex = expf(pd * 0.25f + battn[ekj] * dw);
        den += ex;
        float v0, v1; bf2x(vw, v0, v1);
        acc0 += ex * (v0 + ae0);
        acc1 += ex * (v1 + ae1);
    }
    const float inv = (den > 0.f) ? 1.f / den : 0.f;
    const int64_t base = (int64_t)e * D_DIM;
    const float x0 = acc0 * inv + bond[base + d0];
    const float x1 = acc1 * inv + bond[base + d0 + 1];
    he[base + d0]     = x0;
    he[base + d0 + 1] = x1;
    float sum = x0 + x1;
    #pragma unroll
    for (int o = 32; o > 0; o >>= 1) sum += __shfl_xor(sum, o);
    const float mean = sum * (1.f / 128.f);
    const float dx0 = x0 - mean, dx1 = x1 - mean;
    float var = dx0 * dx0 + dx1 * dx1;
    #pragma unroll
    for (int o = 32; o > 0; o >>= 1) var += __shfl_xor(var, o);
    const float rs = rsqrtf(var * (1.f / 128.f) + 1e-5f);
    const float h0v = dx0 * rs * g1[d0]     + b1[d0];
    const float h1v = dx1 * rs * g1[d0 + 1] + b1[d0 + 1];
    *(unsigned*)&hbf[base + d0] =
        (unsigned)f2bf(h0v) | ((unsigned)f2bf(h1v) << 16);
}

// ---------------------------------------------------------------------------
// FUSED FFN (GEMM1 -> LDS -> GEMM2) + residual + LN2 -> d_out.
// B-REUSE layout (proven R22): each wave owns ALL 64 rows x (N/4) columns.
// he prefetched into registers at entry.
// ---------------------------------------------------------------------------
__launch_bounds__(256)
__global__ void ffn_fused(const unsigned short* __restrict__ hbf,
                          const unsigned short* __restrict__ W1t,
                          const unsigned short* __restrict__ W2t,
                          const float* __restrict__ he,
                          const float* __restrict__ g2, const float* __restrict__ b2,
                          float* __restrict__ outp)
{
    __shared__ __align__(16) unsigned char lds[64 * 264 * 2];   // 33,792 B
    unsigned short* ms = (unsigned short*)lds;                  // [64][264] bf16
    float (*cs)[132] = (float(*)[132])lds;                      // [64][132] f32
    const int lane = threadIdx.x & 63, w = threadIdx.x >> 6;
    const int base_row = blockIdx.x * 64;
    const int lr = lane & 15, g = lane >> 4;

    // ---- prefetch he for the epilogue (wave's 16 rows) ----
    float hev0[16], hev1[16];
    #pragma unroll
    for (int i = 0; i < 16; ++i) {
        const int64_t rg = (int64_t)(base_row + w * 16 + i) * 128;
        hev0[i] = he[rg + lane];
        hev1[i] = he[rg + 64 + lane];
    }

    // ---- GEMM1: wave w -> cols [w*64, w*64+64), all 64 rows; K=128 ----
    {
        f32x4 acc[4][4];
        #pragma unroll
        for (int m = 0; m < 4; ++m)
            #pragma unroll
            for (int n = 0; n < 4; ++n) acc[m][n] = (f32x4){0.f, 0.f, 0.f, 0.f};
        #pragma unroll
        for (int kk = 0; kk < 4; ++kk) {
            bf16x8 a[4], b[4];
            #pragma unroll
            for (int m = 0; m < 4; ++m)
                a[m] = *(const bf16x8*)&hbf[(int64_t)(base_row + m * 16 + lr) * 128 + kk * 32 + g * 8];
            #pragma unroll
            for (int n = 0; n < 4; ++n)
                b[n] = *(const bf16x8*)&W1t[((w * 4 + n) * 16 + lr) * 128 + kk * 32 + g * 8];
            #pragma unroll
            for (int m = 0; m < 4; ++m)
                #pragma unroll
                for (int n = 0; n < 4; ++n)
                    acc[m][n] = __builtin_amdgcn_mfma_f32_16x16x32_bf16(a[m], b[n], acc[m][n], 0, 0, 0);
        }
        #pragma unroll
        for (int m = 0; m < 4; ++m)
            #pragma unroll
            for (int n = 0; n < 4; ++n)
                #pragma unroll
                for (int r = 0; r < 4; ++r) {
                    float v = acc[m][n][r];
                    v = v > 0.f ? v : 0.f;
                    ms[(m * 16 + g * 4 + r) * 264 + (w * 4 + n) * 16 + lr] = f2bf(v);
                }
    }
    __syncthreads();

    // ---- GEMM2: wave w -> cols [w*32, w*32+32), all 64 rows; K=256 ----
    f32x4 acc2[4][2];
    #pragma unroll
    for (int m = 0; m < 4; ++m)
        #pragma unroll
        for (int n = 0; n < 2; ++n) acc2[m][n] = (f32x4){0.f, 0.f, 0.f, 0.f};
    #pragma unroll
    for (int kk = 0; kk < 8; ++kk) {
        bf16x8 a[4], b[2];
        #pragma unroll
        for (int m = 0; m < 4; ++m)
            a[m] = *(const bf16x8*)&ms[(m * 16 + lr) * 264 + kk * 32 + g * 8];
        #pragma unroll
        for (int n = 0; n < 2; ++n)
            b[n] = *(const bf16x8*)&W2t[((w * 2 + n) * 16 + lr) * 256 + kk * 32 + g * 8];
        #pragma unroll
        for (int m = 0; m < 4; ++m)
            #pragma unroll
            for (int n = 0; n < 2; ++n)
                acc2[m][n] = __builtin_amdgcn_mfma_f32_16x16x32_bf16(a[m], b[n], acc2[m][n], 0, 0, 0);
    }
    __syncthreads();   // all ms reads done before cs overwrites the region
    #pragma unroll
    for (int m = 0; m < 4; ++m)
        #pragma unroll
        for (int n = 0; n < 2; ++n)
            #pragma unroll
            for (int r = 0; r < 4; ++r)
                cs[m * 16 + g * 4 + r][w * 32 + n * 16 + lr] = acc2[m][n][r];
    __syncthreads();

    // ---- residual + LN2 on the wave's own 16 rows (registers only) ----
    #pragma unroll 2
    for (int i = 0; i < 16; ++i) {
        const int row = w * 16 + i;
        const int64_t rg = (int64_t)(base_row + row) * 128;
        float x0 = cs[row][lane]      + hev0[i];
        float x1 = cs[row][64 + lane] + hev1[i];
        float s = x0 + x1;
        #pragma unroll
        for (int o = 32; o > 0; o >>= 1) s += __shfl_xor(s, o);
        const float mean = s * (1.f / 128.f);
        const float d0 = x0 - mean, d1 = x1 - mean;
        float v = d0 * d0 + d1 * d1;
        #pragma unroll
        for (int o = 32; o > 0; o >>= 1) v += __shfl_xor(v, o);
        const float rs = rsqrtf(v * (1.f / 128.f) + 1e-5f);
        outp[rg + lane]      = d0 * rs * g2[lane]      + b2[lane];
        outp[rg + 64 + lane] = d1 * rs * g2[lane + 64] + b2[lane + 64];
    }
}

// ---------------------------------------------------------------------------
extern "C" void kernel_launch(void* const* d_in, const int* in_sizes, int n_in,
                              void* d_out, int out_size, void* d_ws, size_t ws_size,
                              hipStream_t stream)
{
    const float* bond     = (const float*)d_in[0];
    const float* pos      = (const float*)d_in[1];
    const float* battn    = (const float*)d_in[2];
    const float* ang_tab  = (const float*)d_in[3];
    const float* ang_in_W = (const float*)d_in[4];
    const float* ang_in_b = (const float*)d_in[5];
    const float* ang2_W   = (const float*)d_in[6];
    const float* ang2_b   = (const float*)d_in[7];
    const float* ang1_W   = (const float*)d_in[8];
    const float* ang1_b   = (const float*)d_in[9];
    const float* k_W      = (const float*)d_in[10];
    const float* q_W      = (const float*)d_in[11];
    const float* v_W      = (const float*)d_in[12];
    const float* dis_W    = (const float*)d_in[13];
    const float* ffn_W1   = (const float*)d_in[14];
    const float* ffn_W2   = (const float*)d_in[15];
    const float* ln1_g    = (const float*)d_in[16];
    const float* ln1_b    = (const float*)d_in[17];
    const float* ln2_g    = (const float*)d_in[18];
    const float* ln2_b    = (const float*)d_in[19];
    const int*   index_kj = (const int*)d_in[20];
    const int*   index_ji = (const int*)d_in[21];
    const int*   idx_i    = (const int*)d_in[22];
    const int*   idx_j    = (const int*)d_in[23];
    const int*   idx_k    = (const int*)d_in[24];

    float* ws = (float*)d_ws;
    // ws layout (float offsets) — ~211 MB, no overlaps
    int*            bins  = (int*)(ws + 0);          //   400,000
    int*            slot  = (int*)(ws + 400000);     //   400,000
    int*            offs  = (int*)(ws + 800000);     //   200,000
    int*            cnt   = (int*)(ws + 1000000);    //   200,000
    int*            cur   = (int*)(ws + 1200000);    //   200,000 (contiguous w/ cnt)
    int*            bsum  = (int*)(ws + 1400000);    //     1,024
    float*          aeT   = ws + 1401088;            //       768
    unsigned short* W1t   = (unsigned short*)(ws + 1401856);   // 32,768 us
    unsigned short* W2t   = (unsigned short*)(ws + 1418240);   // 32,768 us
    unsigned short* Wt    = (unsigned short*)(ws + 1434624);   // 49,152 us
    float*          heb   = ws + 1459200;            // 25,600,000
    unsigned short* hbf   = (unsigned short*)(ws + 27059200); // 25.6M us
    unsigned short* Qh    = (unsigned short*)(ws + 39859200); // 25.6M us

    // d_out holds KVh (E x 256 bf16 = exactly out bytes), then final out
    unsigned short* KVh = (unsigned short*)d_out;
    float*          out = (float*)d_out;

    hipMemsetAsync(cnt, 0, (size_t)2 * E_EDGES * sizeof(int), stream);  // cnt+cur

    ang_mlp_kernel<<<1, 256, 0, stream>>>(ang_tab, ang_in_W, ang_in_b,
                                          ang2_W, ang2_b, ang1_W, ang1_b, aeT);
    conv_w_kernel<<<192, 256, 0, stream>>>(k_W, q_W, v_W, ffn_W1, ffn_W2, Wt, W1t, W2t);
    tri_bins_kernel<<<(T_TRI + 255) / 256, 256, 0, stream>>>(
        pos, idx_i, idx_j, idx_k, index_ji, bins, cnt);

    const int NB = (E_EDGES + 255) / 256;    // 782
    scan1_kernel<<<NB, 256, 0, stream>>>(cnt, offs, bsum);
    scan2_kernel<<<1, 1024, 0, stream>>>(bsum, NB);
    scan3_kernel<<<NB, 256, 0, stream>>>(offs, bsum);
    fill_kernel<<<(T_TRI + 255) / 256, 256, 0, stream>>>(index_ji, offs, cur, slot);

    proj_mfma<<<E_EDGES / 64, 256, 0, stream>>>(bond, Wt, KVh, Qh);

    edge_att_kernel<<<E_EDGES / 4, 256, 0, stream>>>(
        KVh, Qh, aeT, bins, index_kj, slot, offs, cnt,
        battn, dis_W, bond, ln1_g, ln1_b, heb, hbf);

    ffn_fused<<<E_EDGES / 64, 256, 0, stream>>>(hbf, W1t, W2t, heb, ln2_g, ln2_b, out);
}

// Round 24
// 531.794 us; speedup vs baseline: 1.4888x; 1.0604x over previous
//
#include <hip/hip_runtime.h>
#include <cstdint>
#include <math.h>

// Problem constants (match reference)
#define N_ATOMS 30000
#define E_EDGES 200000
#define T_TRI   400000
#define D_DIM   128
#define H_HEADS 8
#define F_FEAT  16
#define CLS     6

typedef __attribute__((ext_vector_type(8))) short bf16x8;
typedef __attribute__((ext_vector_type(4))) float f32x4;

// bf16 helpers (RNE pack, bit-shift unpack)
static __device__ __forceinline__ unsigned short f2bf(float f) {
    union { float f; unsigned u; } v; v.f = f;
    unsigned r = v.u + 0x7FFFu + ((v.u >> 16) & 1u);
    return (unsigned short)(r >> 16);
}
static __device__ __forceinline__ void bf2x(unsigned u, float& a, float& b) {
    union { unsigned u; float f; } x, y;
    x.u = u << 16; y.u = u & 0xFFFF0000u;
    a = x.f; b = y.f;
}
static __device__ __forceinline__ float bf2f(unsigned short u) {
    union { unsigned u; float f; } x; x.u = ((unsigned)u) << 16; return x.f;
}

// ---------------------------------------------------------------------------
// Kernel 1: 6-row angle MLP -> ae_table[6][128]
// ---------------------------------------------------------------------------
__launch_bounds__(256)
__global__ void ang_mlp_kernel(const float* __restrict__ tab,
                               const float* __restrict__ W0, const float* __restrict__ b0,
                               const float* __restrict__ W1, const float* __restrict__ b1,
                               const float* __restrict__ W2, const float* __restrict__ b2,
                               float* __restrict__ out)
{
    __shared__ float bufA[CLS * D_DIM];
    __shared__ float bufB[CLS * D_DIM];
    __shared__ float Wl[D_DIM * D_DIM];
    const int tid = threadIdx.x;
    for (int i = tid; i < CLS * D_DIM; i += 256) bufA[i] = tab[i];
    const float* Ws[3] = {W0, W1, W2};
    const float* bs[3] = {b0, b1, b2};
    float* in  = bufA;
    float* ob  = bufB;
    for (int l = 0; l < 3; ++l) {
        __syncthreads();
        for (int i = tid * 4; i < D_DIM * D_DIM; i += 256 * 4)
            *(float4*)&Wl[i] = *(const float4*)&Ws[l][i];
        __syncthreads();
        for (int o = tid; o < CLS * D_DIM; o += 256) {
            const int r = o >> 7, c = o & 127;
            float acc = bs[l][c];
            #pragma unroll 8
            for (int k = 0; k < D_DIM; ++k) acc += in[r * D_DIM + k] * Wl[k * D_DIM + c];
            ob[o] = fmaxf(acc, 0.f);
        }
        float* t = in; in = ob; ob = t;
    }
    __syncthreads();
    for (int i = tid; i < CLS * D_DIM; i += 256) out[i] = in[i];
}

// ---------------------------------------------------------------------------
// Kernel 2: bins (with atan2(+0,-0) degenerate-sign fix) + per-edge count.
// ---------------------------------------------------------------------------
__launch_bounds__(256)
__global__ void tri_bins_kernel(const float* __restrict__ pos,
                                const int* __restrict__ idx_i,
                                const int* __restrict__ idx_j,
                                const int* __restrict__ idx_k,
                                const int* __restrict__ iji,
                                int* __restrict__ bins,
                                int* __restrict__ cnt)
{
    const int t = blockIdx.x * 256 + threadIdx.x;
    if (t >= T_TRI) return;
    const int ii = idx_i[t], jj = idx_j[t], kk = idx_k[t];
    const float pix = pos[3*ii], piy = pos[3*ii+1], piz = pos[3*ii+2];
    const float jx = __fsub_rn(pos[3*jj],   pix);
    const float jy = __fsub_rn(pos[3*jj+1], piy);
    const float jz = __fsub_rn(pos[3*jj+2], piz);
    const float kx = __fsub_rn(pos[3*kk],   pix);
    const float ky = __fsub_rn(pos[3*kk+1], piy);
    const float kz = __fsub_rn(pos[3*kk+2], piz);
    const float a  = __fadd_rn(__fadd_rn(__fmul_rn(jx,kx), __fmul_rn(jy,ky)),
                               __fmul_rn(jz,kz));
    const float cx = __fsub_rn(__fmul_rn(jy,kz), __fmul_rn(jz,ky));
    const float cy = __fsub_rn(__fmul_rn(jz,kx), __fmul_rn(jx,kz));
    const float cz = __fsub_rn(__fmul_rn(jx,ky), __fmul_rn(jy,kx));
    const float ss = __fadd_rn(__fadd_rn(__fmul_rn(cx,cx), __fmul_rn(cy,cy)),
                               __fmul_rn(cz,cz));
    const float b  = __fsqrt_rn(ss);

    int bin;
    if (b == 0.0f && __float_as_uint(a) == 0x80000000u) {
        bin = 0;   // atan2(+0,-0): IEEE pi (bin 5) vs reference SVML 0 (bin 0)
    } else {
        const float angle = (float)atan2((double)b, (double)a);
        const float c = (float)(3.1415926 / 6.0);
        const float q = __fdiv_rn(angle, c);
        bin = (int)q;
        bin = bin < 0 ? 0 : (bin > CLS - 1 ? CLS - 1 : bin);
    }
    bins[t] = bin;
    atomicAdd(&cnt[iji[t]], 1);
}

// ---------------------------------------------------------------------------
// CSR build: block-scan (3 kernels) + scatter fill
// ---------------------------------------------------------------------------
__launch_bounds__(256)
__global__ void scan1_kernel(const int* __restrict__ cnt, int* __restrict__ offs,
                             int* __restrict__ bsum)
{
    __shared__ int buf[256];
    const int i = blockIdx.x * 256 + threadIdx.x;
    const int v = (i < E_EDGES) ? cnt[i] : 0;
    buf[threadIdx.x] = v;
    __syncthreads();
    for (int o = 1; o < 256; o <<= 1) {
        const int t = (threadIdx.x >= o) ? buf[threadIdx.x - o] : 0;
        __syncthreads();
        buf[threadIdx.x] += t;
        __syncthreads();
    }
    if (i < E_EDGES) offs[i] = buf[threadIdx.x] - v;
    if (threadIdx.x == 255) bsum[blockIdx.x] = buf[255];
}

__launch_bounds__(1024)
__global__ void scan2_kernel(int* __restrict__ bsum, int nb)
{
    __shared__ int buf[1024];
    const int tid = threadIdx.x;
    const int v = (tid < nb) ? bsum[tid] : 0;
    buf[tid] = v;
    __syncthreads();
    for (int o = 1; o < 1024; o <<= 1) {
        const int t = (tid >= o) ? buf[tid - o] : 0;
        __syncthreads();
        buf[tid] += t;
        __syncthreads();
    }
    if (tid < nb) bsum[tid] = buf[tid] - v;   // exclusive
}

__launch_bounds__(256)
__global__ void scan3_kernel(int* __restrict__ offs, const int* __restrict__ bsum)
{
    const int i = blockIdx.x * 256 + threadIdx.x;
    if (i < E_EDGES) offs[i] += bsum[blockIdx.x];
}

__launch_bounds__(256)
__global__ void fill_kernel(const int* __restrict__ iji, const int* __restrict__ offs,
                            int* __restrict__ cur, int* __restrict__ slot)
{
    const int t = blockIdx.x * 256 + threadIdx.x;
    if (t >= T_TRI) return;
    const int e = iji[t];
    const int p = offs[e] + atomicAdd(&cur[e], 1);
    slot[p] = t;
}

// ---------------------------------------------------------------------------
// Weight convert: Wt[384][128] = [kW|qW|vW]^T bf16;  W1t[256][128], W2t[128][256]
// ---------------------------------------------------------------------------
__launch_bounds__(256)
__global__ void conv_w_kernel(const float* __restrict__ kW, const float* __restrict__ qW,
                              const float* __restrict__ vW,
                              const float* __restrict__ W1, const float* __restrict__ W2,
                              unsigned short* __restrict__ Wt,
                              unsigned short* __restrict__ W1t,
                              unsigned short* __restrict__ W2t)
{
    const int i = blockIdx.x * 256 + threadIdx.x;
    if (i < 384 * 128) {               // Wt[n][k]
        const int n = i >> 7, k = i & 127;
        const int sel = n >> 7, c = n & 127;
        const float* W = (sel == 0) ? kW : (sel == 1) ? qW : vW;
        Wt[i] = f2bf(W[k * 128 + c]);
    }
    if (i < 128 * 256) {
        { const int n = i >> 7, k = i & 127;  W1t[n * 128 + k] = f2bf(W1[k * 256 + n]); }
        { const int n = i >> 8, k = i & 255;  W2t[n * 256 + k] = f2bf(W2[k * 128 + n]); }
    }
}

// ---------------------------------------------------------------------------
// Fused K/Q/V projection (MFMA) with B-REUSE (proven R22/R23).
// Output: KVh[E][256] (K cols 0-127, V cols 128-255), Qh[E][128].
// ---------------------------------------------------------------------------
__launch_bounds__(256)
__global__ void proj_mfma(const float* __restrict__ bond,
                          const unsigned short* __restrict__ Wt,
                          unsigned short* __restrict__ KVh,
                          unsigned short* __restrict__ Qh)
{
    __shared__ unsigned short ms[64 * 392];   // pitch 392 breaks bank alias
    const int lane = threadIdx.x & 63, w = threadIdx.x >> 6;
    const int base_row = blockIdx.x * 64;
    const int lr = lane & 15, g = lane >> 4;
    f32x4 acc[4][6];
    #pragma unroll
    for (int m = 0; m < 4; ++m)
        #pragma unroll
        for (int n = 0; n < 6; ++n) acc[m][n] = (f32x4){0.f, 0.f, 0.f, 0.f};
    #pragma unroll
    for (int kk = 0; kk < 4; ++kk) {
        bf16x8 a[4], b[6];
        #pragma unroll
        for (int m = 0; m < 4; ++m) {
            const int64_t ab = (int64_t)(base_row + m * 16 + lr) * 128 + kk * 32 + g * 8;
            const float4 f0 = *(const float4*)&bond[ab];
            const float4 f1 = *(const float4*)&bond[ab + 4];
            a[m][0] = (short)f2bf(f0.x); a[m][1] = (short)f2bf(f0.y);
            a[m][2] = (short)f2bf(f0.z); a[m][3] = (short)f2bf(f0.w);
            a[m][4] = (short)f2bf(f1.x); a[m][5] = (short)f2bf(f1.y);
            a[m][6] = (short)f2bf(f1.z); a[m][7] = (short)f2bf(f1.w);
        }
        #pragma unroll
        for (int n = 0; n < 6; ++n)
            b[n] = *(const bf16x8*)&Wt[((w * 6 + n) * 16 + lr) * 128 + kk * 32 + g * 8];
        #pragma unroll
        for (int m = 0; m < 4; ++m)
            #pragma unroll
            for (int n = 0; n < 6; ++n)
                acc[m][n] = __builtin_amdgcn_mfma_f32_16x16x32_bf16(a[m], b[n], acc[m][n], 0, 0, 0);
    }
    #pragma unroll
    for (int m = 0; m < 4; ++m)
        #pragma unroll
        for (int n = 0; n < 6; ++n)
            #pragma unroll
            for (int r = 0; r < 4; ++r)
                ms[(m * 16 + g * 4 + r) * 392 + (w * 6 + n) * 16 + lr] = f2bf(acc[m][n][r]);
    __syncthreads();
    // cols 0-127 = K -> KV[0..127]; 128-255 = Q -> Q; 256-383 = V -> KV[128..255]
    for (int idx = threadIdx.x; idx < 64 * 48; idx += 256) {
        const int row = idx / 48, c8 = (idx % 48) * 8;
        const int e = base_row + row;
        const uint4 v = *(const uint4*)&ms[row * 392 + c8];
        if (c8 < 128)       *(uint4*)&KVh[(int64_t)e * 256 + c8] = v;
        else if (c8 < 256)  *(uint4*)&Qh[(int64_t)e * 128 + (c8 - 128)] = v;
        else                *(uint4*)&KVh[(int64_t)e * 256 + 128 + (c8 - 256)] = v;
    }
}

// ---------------------------------------------------------------------------
// FUSED per-edge attention + aggregation + he + LN1.
// Outputs he as bf16 (hef) and h as bf16 (hbf).  Triplet loop software-
// pipelined: next iteration's slot/ikj/bins/KV/battn are issued before the
// current iteration's shfl+exp dependency chain.
// ---------------------------------------------------------------------------
__launch_bounds__(256)
__global__ void edge_att_kernel(const unsigned short* __restrict__ KVh,
                                const unsigned short* __restrict__ Qh,
                                const float* __restrict__ aeT,
                                const int* __restrict__ bins,
                                const int* __restrict__ ikj,
                                const int* __restrict__ slot,
                                const int* __restrict__ offs,
                                const int* __restrict__ cnt,
                                const float* __restrict__ battn,
                                const float* __restrict__ disW,
                                const float* __restrict__ bond,
                                const float* __restrict__ g1,
                                const float* __restrict__ b1,
                                unsigned short* __restrict__ hef,
                                unsigned short* __restrict__ hbf)
{
    __shared__ float aeL[CLS * D_DIM];
    for (int i = threadIdx.x; i < CLS * D_DIM; i += 256) aeL[i] = aeT[i];
    __syncthreads();
    const int wid  = threadIdx.x >> 6;
    const int lane = threadIdx.x & 63;
    const int e = blockIdx.x * 4 + wid;
    const int d0 = lane * 2;
    const int h  = lane >> 3;
    const float dw = disW[h];

    unsigned qw = *(const unsigned*)&Qh[(int64_t)e * D_DIM + d0];
    float q0, q1; bf2x(qw, q0, q1);

    float acc0 = 0.f, acc1 = 0.f, den = 0.f;
    const int start = offs[e], n = cnt[e];
    int bin = 0; unsigned kw = 0, vw = 0; float bat = 0.f;
    if (n > 0) {
        const int t0 = slot[start];
        bin = bins[t0];
        const int ekj0 = ikj[t0];
        const int64_t kvb = (int64_t)ekj0 * 256;
        kw = *(const unsigned*)&KVh[kvb + d0];
        vw = *(const unsigned*)&KVh[kvb + 128 + d0];
        bat = battn[ekj0];
    }
    for (int s = 0; s < n; ++s) {
        const int bin_c = bin;
        const unsigned kw_c = kw, vw_c = vw;
        const float bat_c = bat;
        if (s + 1 < n) {                       // prefetch next triplet
            const int t1 = slot[start + s + 1];
            bin = bins[t1];
            const int ekj1 = ikj[t1];
            const int64_t kvb = (int64_t)ekj1 * 256;
            kw = *(const unsigned*)&KVh[kvb + d0];
            vw = *(const unsigned*)&KVh[kvb + 128 + d0];
            bat = battn[ekj1];
        }
        const float ae0 = aeL[bin_c * D_DIM + d0];
        const float ae1 = aeL[bin_c * D_DIM + d0 + 1];
        float k0, k1; bf2x(kw_c, k0, k1);
        float pd = (k0 + ae0) * (q0 + ae0) + (k1 + ae1) * (q1 + ae1);
        pd += __shfl_xor(pd, 1);
        pd += __shfl_xor(pd, 2);
        pd += __shfl_xor(pd, 4);
        const float ex = expf(pd * 0.25f + bat_c * dw);
        den += ex;
        float v0, v1; bf2x(vw_c, v0, v1);
        acc0 += ex * (v0 + ae0);
        acc1 += ex * (v1 + ae1);
    }
    const float inv = (den > 0.f) ? 1.f / den : 0.f;
    const int64_t base = (int64_t)e * D_DIM;
    const float x0 = acc0 * inv + bond[base + d0];
    const float x1 = acc1 * inv + bond[base + d0 + 1];
    *(unsigned*)&hef[base + d0] =
        (unsigned)f2bf(x0) | ((unsigned)f2bf(x1) << 16);
    float sum = x0 + x1;
    #pragma unroll
    for (int o = 32; o > 0; o >>= 1) sum += __shfl_xor(sum, o);
    const float mean = sum * (1.f / 128.f);
    const float dx0 = x0 - mean, dx1 = x1 - mean;
    float var = dx0 * dx0 + dx1 * dx1;
    #pragma unroll
    for (int o = 32; o > 0; o >>= 1) var += __shfl_xor(var, o);
    const float rs = rsqrtf(var * (1.f / 128.f) + 1e-5f);
    const float h0v = dx0 * rs * g1[d0]     + b1[d0];
    const float h1v = dx1 * rs * g1[d0 + 1] + b1[d0 + 1];
    *(unsigned*)&hbf[base + d0] =
        (unsigned)f2bf(h0v) | ((unsigned)f2bf(h1v) << 16);
}

// ---------------------------------------------------------------------------
// FUSED FFN (GEMM1 -> LDS -> GEMM2) + residual + LN2 -> d_out.
// B-REUSE layout; he (bf16) prefetched into registers at entry.
// ---------------------------------------------------------------------------
__launch_bounds__(256)
__global__ void ffn_fused(const unsigned short* __restrict__ hbf,
                          const unsigned short* __restrict__ W1t,
                          const unsigned short* __restrict__ W2t,
                          const unsigned short* __restrict__ hef,
                          const float* __restrict__ g2, const float* __restrict__ b2,
                          float* __restrict__ outp)
{
    __shared__ __align__(16) unsigned char lds[64 * 264 * 2];   // 33,792 B
    unsigned short* ms = (unsigned short*)lds;                  // [64][264] bf16
    float (*cs)[132] = (float(*)[132])lds;                      // [64][132] f32
    const int lane = threadIdx.x & 63, w = threadIdx.x >> 6;
    const int base_row = blockIdx.x * 64;
    const int lr = lane & 15, g = lane >> 4;

    // ---- prefetch he (bf16) for the epilogue (wave's 16 rows) ----
    unsigned short heu0[16], heu1[16];
    #pragma unroll
    for (int i = 0; i < 16; ++i) {
        const int64_t rg = (int64_t)(base_row + w * 16 + i) * 128;
        heu0[i] = hef[rg + lane];
        heu1[i] = hef[rg + 64 + lane];
    }

    // ---- GEMM1: wave w -> cols [w*64, w*64+64), all 64 rows; K=128 ----
    {
        f32x4 acc[4][4];
        #pragma unroll
        for (int m = 0; m < 4; ++m)
            #pragma unroll
            for (int n = 0; n < 4; ++n) acc[m][n] = (f32x4){0.f, 0.f, 0.f, 0.f};
        #pragma unroll
        for (int kk = 0; kk < 4; ++kk) {
            bf16x8 a[4], b[4];
            #pragma unroll
            for (int m = 0; m < 4; ++m)
                a[m] = *(const bf16x8*)&hbf[(int64_t)(base_row + m * 16 + lr) * 128 + kk * 32 + g * 8];
            #pragma unroll
            for (int n = 0; n < 4; ++n)
                b[n] = *(const bf16x8*)&W1t[((w * 4 + n) * 16 + lr) * 128 + kk * 32 + g * 8];
            #pragma unroll
            for (int m = 0; m < 4; ++m)
                #pragma unroll
                for (int n = 0; n < 4; ++n)
                    acc[m][n] = __builtin_amdgcn_mfma_f32_16x16x32_bf16(a[m], b[n], acc[m][n], 0, 0, 0);
        }
        #pragma unroll
        for (int m = 0; m < 4; ++m)
            #pragma unroll
            for (int n = 0; n < 4; ++n)
                #pragma unroll
                for (int r = 0; r < 4; ++r) {
                    float v = acc[m][n][r];
                    v = v > 0.f ? v : 0.f;
                    ms[(m * 16 + g * 4 + r) * 264 + (w * 4 + n) * 16 + lr] = f2bf(v);
                }
    }
    __syncthreads();

    // ---- GEMM2: wave w -> cols [w*32, w*32+32), all 64 rows; K=256 ----
    f32x4 acc2[4][2];
    #pragma unroll
    for (int m = 0; m < 4; ++m)
        #pragma unroll
        for (int n = 0; n < 2; ++n) acc2[m][n] = (f32x4){0.f, 0.f, 0.f, 0.f};
    #pragma unroll
    for (int kk = 0; kk < 8; ++kk) {
        bf16x8 a[4], b[2];
        #pragma unroll
        for (int m = 0; m < 4; ++m)
            a[m] = *(const bf16x8*)&ms[(m * 16 + lr) * 264 + kk * 32 + g * 8];
        #pragma unroll
        for (int n = 0; n < 2; ++n)
            b[n] = *(const bf16x8*)&W2t[((w * 2 + n) * 16 + lr) * 256 + kk * 32 + g * 8];
        #pragma unroll
        for (int m = 0; m < 4; ++m)
            #pragma unroll
            for (int n = 0; n < 2; ++n)
                acc2[m][n] = __builtin_amdgcn_mfma_f32_16x16x32_bf16(a[m], b[n], acc2[m][n], 0, 0, 0);
    }
    __syncthreads();   // all ms reads done before cs overwrites the region
    #pragma unroll
    for (int m = 0; m < 4; ++m)
        #pragma unroll
        for (int n = 0; n < 2; ++n)
            #pragma unroll
            for (int r = 0; r < 4; ++r)
                cs[m * 16 + g * 4 + r][w * 32 + n * 16 + lr] = acc2[m][n][r];
    __syncthreads();

    // ---- residual + LN2 on the wave's own 16 rows (registers only) ----
    #pragma unroll 2
    for (int i = 0; i < 16; ++i) {
        const int row = w * 16 + i;
        const int64_t rg = (int64_t)(base_row + row) * 128;
        float x0 = cs[row][lane]      + bf2f(heu0[i]);
        float x1 = cs[row][64 + lane] + bf2f(heu1[i]);
        float s = x0 + x1;
        #pragma unroll
        for (int o = 32; o > 0; o >>= 1) s += __shfl_xor(s, o);
        const float mean = s * (1.f / 128.f);
        const float d0 = x0 - mean, d1 = x1 - mean;
        float v = d0 * d0 + d1 * d1;
        #pragma unroll
        for (int o = 32; o > 0; o >>= 1) v += __shfl_xor(v, o);
        const float rs = rsqrtf(v * (1.f / 128.f) + 1e-5f);
        outp[rg + lane]      = d0 * rs * g2[lane]      + b2[lane];
        outp[rg + 64 + lane] = d1 * rs * g2[lane + 64] + b2[lane + 64];
    }
}

// ---------------------------------------------------------------------------
extern "C" void kernel_launch(void* const* d_in, const int* in_sizes, int n_in,
                              void* d_out, int out_size, void* d_ws, size_t ws_size,
                              hipStream_t stream)
{
    const float* bond     = (const float*)d_in[0];
    const float* pos      = (const float*)d_in[1];
    const float* battn    = (const float*)d_in[2];
    const float* ang_tab  = (const float*)d_in[3];
    const float* ang_in_W = (const float*)d_in[4];
    const float* ang_in_b = (const float*)d_in[5];
    const float* ang2_W   = (const float*)d_in[6];
    const float* ang2_b   = (const float*)d_in[7];
    const float* ang1_W   = (const float*)d_in[8];
    const float* ang1_b   = (const float*)d_in[9];
    const float* k_W      = (const float*)d_in[10];
    const float* q_W      = (const float*)d_in[11];
    const float* v_W      = (const float*)d_in[12];
    const float* dis_W    = (const float*)d_in[13];
    const float* ffn_W1   = (const float*)d_in[14];
    const float* ffn_W2   = (const float*)d_in[15];
    const float* ln1_g    = (const float*)d_in[16];
    const float* ln1_b    = (const float*)d_in[17];
    const float* ln2_g    = (const float*)d_in[18];
    const float* ln2_b    = (const float*)d_in[19];
    const int*   index_kj = (const int*)d_in[20];
    const int*   index_ji = (const int*)d_in[21];
    const int*   idx_i    = (const int*)d_in[22];
    const int*   idx_j    = (const int*)d_in[23];
    const int*   idx_k    = (const int*)d_in[24];

    float* ws = (float*)d_ws;
    // ws layout (float offsets) — ~160 MB, no overlaps
    int*            bins  = (int*)(ws + 0);          //   400,000
    int*            slot  = (int*)(ws + 400000);     //   400,000
    int*            offs  = (int*)(ws + 800000);     //   200,000
    int*            cnt   = (int*)(ws + 1000000);    //   200,000
    int*            cur   = (int*)(ws + 1200000);    //   200,000 (contiguous w/ cnt)
    int*            bsum  = (int*)(ws + 1400000);    //     1,024
    float*          aeT   = ws + 1401088;            //       768
    unsigned short* W1t   = (unsigned short*)(ws + 1401856);   // 32,768 us
    unsigned short* W2t   = (unsigned short*)(ws + 1418240);   // 32,768 us
    unsigned short* Wt    = (unsigned short*)(ws + 1434624);   // 49,152 us
    unsigned short* hef   = (unsigned short*)(ws + 1459200);   // 25.6M us (12.8M f)
    unsigned short* hbf   = (unsigned short*)(ws + 14259200);  // 25.6M us
    unsigned short* Qh    = (unsigned short*)(ws + 27059200);  // 25.6M us

    // d_out holds KVh (E x 256 bf16 = exactly out bytes), then final out
    unsigned short* KVh = (unsigned short*)d_out;
    float*          out = (float*)d_out;

    hipMemsetAsync(cnt, 0, (size_t)2 * E_EDGES * sizeof(int), stream);  // cnt+cur

    ang_mlp_kernel<<<1, 256, 0, stream>>>(ang_tab, ang_in_W, ang_in_b,
                                          ang2_W, ang2_b, ang1_W, ang1_b, aeT);
    conv_w_kernel<<<192, 256, 0, stream>>>(k_W, q_W, v_W, ffn_W1, ffn_W2, Wt, W1t, W2t);
    tri_bins_kernel<<<(T_TRI + 255) / 256, 256, 0, stream>>>(
        pos, idx_i, idx_j, idx_k, index_ji, bins, cnt);

    const int NB = (E_EDGES + 255) / 256;    // 782
    scan1_kernel<<<NB, 256, 0, stream>>>(cnt, offs, bsum);
    scan2_kernel<<<1, 1024, 0, stream>>>(bsum, NB);
    scan3_kernel<<<NB, 256, 0, stream>>>(offs, bsum);
    fill_kernel<<<(T_TRI + 255) / 256, 256, 0, stream>>>(index_ji, offs, cur, slot);

    proj_mfma<<<E_EDGES / 64, 256, 0, stream>>>(bond, Wt, KVh, Qh);

    edge_att_kernel<<<E_EDGES / 4, 256, 0, stream>>>(
        KVh, Qh, aeT, bins, index_kj, slot, offs, cnt,
        battn, dis_W, bond, ln1_g, ln1_b, hef, hbf);

    ffn_fused<<<E_EDGES / 64, 256, 0, stream>>>(hbf, W1t, W2t, hef, ln2_g, ln2_b, out);
}

// Round 25
// 525.473 us; speedup vs baseline: 1.5067x; 1.0120x over previous
//
#include <hip/hip_runtime.h>
#include <cstdint>
#include <math.h>

// Problem constants (match reference)
#define N_ATOMS 30000
#define E_EDGES 200000
#define T_TRI   400000
#define D_DIM   128
#define H_HEADS 8
#define F_FEAT  16
#define CLS     6

typedef __attribute__((ext_vector_type(8))) short bf16x8;
typedef __attribute__((ext_vector_type(4))) float f32x4;

// bf16 helpers (RNE pack, bit-shift unpack)
static __device__ __forceinline__ unsigned short f2bf(float f) {
    union { float f; unsigned u; } v; v.f = f;
    unsigned r = v.u + 0x7FFFu + ((v.u >> 16) & 1u);
    return (unsigned short)(r >> 16);
}
static __device__ __forceinline__ void bf2x(unsigned u, float& a, float& b) {
    union { unsigned u; float f; } x, y;
    x.u = u << 16; y.u = u & 0xFFFF0000u;
    a = x.f; b = y.f;
}
static __device__ __forceinline__ float bf2f(unsigned short u) {
    union { unsigned u; float f; } x; x.u = ((unsigned)u) << 16; return x.f;
}

// ---------------------------------------------------------------------------
// Kernel 1: 6-row angle MLP -> ae_table[6][128]
// ---------------------------------------------------------------------------
__launch_bounds__(256)
__global__ void ang_mlp_kernel(const float* __restrict__ tab,
                               const float* __restrict__ W0, const float* __restrict__ b0,
                               const float* __restrict__ W1, const float* __restrict__ b1,
                               const float* __restrict__ W2, const float* __restrict__ b2,
                               float* __restrict__ out)
{
    __shared__ float bufA[CLS * D_DIM];
    __shared__ float bufB[CLS * D_DIM];
    __shared__ float Wl[D_DIM * D_DIM];
    const int tid = threadIdx.x;
    for (int i = tid; i < CLS * D_DIM; i += 256) bufA[i] = tab[i];
    const float* Ws[3] = {W0, W1, W2};
    const float* bs[3] = {b0, b1, b2};
    float* in  = bufA;
    float* ob  = bufB;
    for (int l = 0; l < 3; ++l) {
        __syncthreads();
        for (int i = tid * 4; i < D_DIM * D_DIM; i += 256 * 4)
            *(float4*)&Wl[i] = *(const float4*)&Ws[l][i];
        __syncthreads();
        for (int o = tid; o < CLS * D_DIM; o += 256) {
            const int r = o >> 7, c = o & 127;
            float acc = bs[l][c];
            #pragma unroll 8
            for (int k = 0; k < D_DIM; ++k) acc += in[r * D_DIM + k] * Wl[k * D_DIM + c];
            ob[o] = fmaxf(acc, 0.f);
        }
        float* t = in; in = ob; ob = t;
    }
    __syncthreads();
    for (int i = tid; i < CLS * D_DIM; i += 256) out[i] = in[i];
}

// ---------------------------------------------------------------------------
// Kernel 2: bins (with atan2(+0,-0) degenerate-sign fix) + per-edge count.
// ---------------------------------------------------------------------------
__launch_bounds__(256)
__global__ void tri_bins_kernel(const float* __restrict__ pos,
                                const int* __restrict__ idx_i,
                                const int* __restrict__ idx_j,
                                const int* __restrict__ idx_k,
                                const int* __restrict__ iji,
                                int* __restrict__ bins,
                                int* __restrict__ cnt)
{
    const int t = blockIdx.x * 256 + threadIdx.x;
    if (t >= T_TRI) return;
    const int ii = idx_i[t], jj = idx_j[t], kk = idx_k[t];
    const float pix = pos[3*ii], piy = pos[3*ii+1], piz = pos[3*ii+2];
    const float jx = __fsub_rn(pos[3*jj],   pix);
    const float jy = __fsub_rn(pos[3*jj+1], piy);
    const float jz = __fsub_rn(pos[3*jj+2], piz);
    const float kx = __fsub_rn(pos[3*kk],   pix);
    const float ky = __fsub_rn(pos[3*kk+1], piy);
    const float kz = __fsub_rn(pos[3*kk+2], piz);
    const float a  = __fadd_rn(__fadd_rn(__fmul_rn(jx,kx), __fmul_rn(jy,ky)),
                               __fmul_rn(jz,kz));
    const float cx = __fsub_rn(__fmul_rn(jy,kz), __fmul_rn(jz,ky));
    const float cy = __fsub_rn(__fmul_rn(jz,kx), __fmul_rn(jx,kz));
    const float cz = __fsub_rn(__fmul_rn(jx,ky), __fmul_rn(jy,kx));
    const float ss = __fadd_rn(__fadd_rn(__fmul_rn(cx,cx), __fmul_rn(cy,cy)),
                               __fmul_rn(cz,cz));
    const float b  = __fsqrt_rn(ss);

    int bin;
    if (b == 0.0f && __float_as_uint(a) == 0x80000000u) {
        bin = 0;   // atan2(+0,-0): IEEE pi (bin 5) vs reference SVML 0 (bin 0)
    } else {
        const float angle = (float)atan2((double)b, (double)a);
        const float c = (float)(3.1415926 / 6.0);
        const float q = __fdiv_rn(angle, c);
        bin = (int)q;
        bin = bin < 0 ? 0 : (bin > CLS - 1 ? CLS - 1 : bin);
    }
    bins[t] = bin;
    atomicAdd(&cnt[iji[t]], 1);
}

// ---------------------------------------------------------------------------
// CSR build: block-scan (3 kernels) + scatter fill
// ---------------------------------------------------------------------------
__launch_bounds__(256)
__global__ void scan1_kernel(const int* __restrict__ cnt, int* __restrict__ offs,
                             int* __restrict__ bsum)
{
    __shared__ int buf[256];
    const int i = blockIdx.x * 256 + threadIdx.x;
    const int v = (i < E_EDGES) ? cnt[i] : 0;
    buf[threadIdx.x] = v;
    __syncthreads();
    for (int o = 1; o < 256; o <<= 1) {
        const int t = (threadIdx.x >= o) ? buf[threadIdx.x - o] : 0;
        __syncthreads();
        buf[threadIdx.x] += t;
        __syncthreads();
    }
    if (i < E_EDGES) offs[i] = buf[threadIdx.x] - v;
    if (threadIdx.x == 255) bsum[blockIdx.x] = buf[255];
}

__launch_bounds__(1024)
__global__ void scan2_kernel(int* __restrict__ bsum, int nb)
{
    __shared__ int buf[1024];
    const int tid = threadIdx.x;
    const int v = (tid < nb) ? bsum[tid] : 0;
    buf[tid] = v;
    __syncthreads();
    for (int o = 1; o < 1024; o <<= 1) {
        const int t = (tid >= o) ? buf[tid - o] : 0;
        __syncthreads();
        buf[tid] += t;
        __syncthreads();
    }
    if (tid < nb) bsum[tid] = buf[tid] - v;   // exclusive
}

__launch_bounds__(256)
__global__ void scan3_kernel(int* __restrict__ offs, const int* __restrict__ bsum)
{
    const int i = blockIdx.x * 256 + threadIdx.x;
    if (i < E_EDGES) offs[i] += bsum[blockIdx.x];
}

__launch_bounds__(256)
__global__ void fill_kernel(const int* __restrict__ iji, const int* __restrict__ offs,
                            int* __restrict__ cur, int* __restrict__ slot)
{
    const int t = blockIdx.x * 256 + threadIdx.x;
    if (t >= T_TRI) return;
    const int e = iji[t];
    const int p = offs[e] + atomicAdd(&cur[e], 1);
    slot[p] = t;
}

// ---------------------------------------------------------------------------
// Weight convert: Wt[384][128] = [kW|qW|vW]^T bf16;  W1t[256][128], W2t[128][256]
// ---------------------------------------------------------------------------
__launch_bounds__(256)
__global__ void conv_w_kernel(const float* __restrict__ kW, const float* __restrict__ qW,
                              const float* __restrict__ vW,
                              const float* __restrict__ W1, const float* __restrict__ W2,
                              unsigned short* __restrict__ Wt,
                              unsigned short* __restrict__ W1t,
                              unsigned short* __restrict__ W2t)
{
    const int i = blockIdx.x * 256 + threadIdx.x;
    if (i < 384 * 128) {               // Wt[n][k]
        const int n = i >> 7, k = i & 127;
        const int sel = n >> 7, c = n & 127;
        const float* W = (sel == 0) ? kW : (sel == 1) ? qW : vW;
        Wt[i] = f2bf(W[k * 128 + c]);
    }
    if (i < 128 * 256) {
        { const int n = i >> 7, k = i & 127;  W1t[n * 128 + k] = f2bf(W1[k * 256 + n]); }
        { const int n = i >> 8, k = i & 255;  W2t[n * 256 + k] = f2bf(W2[k * 128 + n]); }
    }
}

// ---------------------------------------------------------------------------
// Fused K/Q/V projection (MFMA) with B-REUSE (proven R22/R23).
// Output: KVh[E][256] (K cols 0-127, V cols 128-255), Qh[E][128].
// ---------------------------------------------------------------------------
__launch_bounds__(256)
__global__ void proj_mfma(const float* __restrict__ bond,
                          const unsigned short* __restrict__ Wt,
                          unsigned short* __restrict__ KVh,
                          unsigned short* __restrict__ Qh)
{
    __shared__ unsigned short ms[64 * 392];   // pitch 392 breaks bank alias
    const int lane = threadIdx.x & 63, w = threadIdx.x >> 6;
    const int base_row = blockIdx.x * 64;
    const int lr = lane & 15, g = lane >> 4;
    f32x4 acc[4][6];
    #pragma unroll
    for (int m = 0; m < 4; ++m)
        #pragma unroll
        for (int n = 0; n < 6; ++n) acc[m][n] = (f32x4){0.f, 0.f, 0.f, 0.f};
    #pragma unroll
    for (int kk = 0; kk < 4; ++kk) {
        bf16x8 a[4], b[6];
        #pragma unroll
        for (int m = 0; m < 4; ++m) {
            const int64_t ab = (int64_t)(base_row + m * 16 + lr) * 128 + kk * 32 + g * 8;
            const float4 f0 = *(const float4*)&bond[ab];
            const float4 f1 = *(const float4*)&bond[ab + 4];
            a[m][0] = (short)f2bf(f0.x); a[m][1] = (short)f2bf(f0.y);
            a[m][2] = (short)f2bf(f0.z); a[m][3] = (short)f2bf(f0.w);
            a[m][4] = (short)f2bf(f1.x); a[m][5] = (short)f2bf(f1.y);
            a[m][6] = (short)f2bf(f1.z); a[m][7] = (short)f2bf(f1.w);
        }
        #pragma unroll
        for (int n = 0; n < 6; ++n)
            b[n] = *(const bf16x8*)&Wt[((w * 6 + n) * 16 + lr) * 128 + kk * 32 + g * 8];
        #pragma unroll
        for (int m = 0; m < 4; ++m)
            #pragma unroll
            for (int n = 0; n < 6; ++n)
                acc[m][n] = __builtin_amdgcn_mfma_f32_16x16x32_bf16(a[m], b[n], acc[m][n], 0, 0, 0);
    }
    #pragma unroll
    for (int m = 0; m < 4; ++m)
        #pragma unroll
        for (int n = 0; n < 6; ++n)
            #pragma unroll
            for (int r = 0; r < 4; ++r)
                ms[(m * 16 + g * 4 + r) * 392 + (w * 6 + n) * 16 + lr] = f2bf(acc[m][n][r]);
    __syncthreads();
    // cols 0-127 = K -> KV[0..127]; 128-255 = Q -> Q; 256-383 = V -> KV[128..255]
    for (int idx = threadIdx.x; idx < 64 * 48; idx += 256) {
        const int row = idx / 48, c8 = (idx % 48) * 8;
        const int e = base_row + row;
        const uint4 v = *(const uint4*)&ms[row * 392 + c8];
        if (c8 < 128)       *(uint4*)&KVh[(int64_t)e * 256 + c8] = v;
        else if (c8 < 256)  *(uint4*)&Qh[(int64_t)e * 128 + (c8 - 128)] = v;
        else                *(uint4*)&KVh[(int64_t)e * 256 + 128 + (c8 - 256)] = v;
    }
}

// ---------------------------------------------------------------------------
// FUSED per-edge attention + aggregation -> attf (bf16, normalized att out).
// bond-add + LN1 moved into ffn_fused (cuts 102 MB bond read + 51 MB write
// here).  Triplet loop software-pipelined.
// ---------------------------------------------------------------------------
__launch_bounds__(256)
__global__ void edge_att_kernel(const unsigned short* __restrict__ KVh,
                                const unsigned short* __restrict__ Qh,
                                const float* __restrict__ aeT,
                                const int* __restrict__ bins,
                                const int* __restrict__ ikj,
                                const int* __restrict__ slot,
                                const int* __restrict__ offs,
                                const int* __restrict__ cnt,
                                const float* __restrict__ battn,
                                const float* __restrict__ disW,
                                unsigned short* __restrict__ attf)
{
    __shared__ float aeL[CLS * D_DIM];
    for (int i = threadIdx.x; i < CLS * D_DIM; i += 256) aeL[i] = aeT[i];
    __syncthreads();
    const int wid  = threadIdx.x >> 6;
    const int lane = threadIdx.x & 63;
    const int e = blockIdx.x * 4 + wid;
    const int d0 = lane * 2;
    const int h  = lane >> 3;
    const float dw = disW[h];

    unsigned qw = *(const unsigned*)&Qh[(int64_t)e * D_DIM + d0];
    float q0, q1; bf2x(qw, q0, q1);

    float acc0 = 0.f, acc1 = 0.f, den = 0.f;
    const int start = offs[e], n = cnt[e];
    int bin = 0; unsigned kw = 0, vw = 0; float bat = 0.f;
    if (n > 0) {
        const int t0 = slot[start];
        bin = bins[t0];
        const int ekj0 = ikj[t0];
        const int64_t kvb = (int64_t)ekj0 * 256;
        kw = *(const unsigned*)&KVh[kvb + d0];
        vw = *(const unsigned*)&KVh[kvb + 128 + d0];
        bat = battn[ekj0];
    }
    for (int s = 0; s < n; ++s) {
        const int bin_c = bin;
        const unsigned kw_c = kw, vw_c = vw;
        const float bat_c = bat;
        if (s + 1 < n) {                       // prefetch next triplet
            const int t1 = slot[start + s + 1];
            bin = bins[t1];
            const int ekj1 = ikj[t1];
            const int64_t kvb = (int64_t)ekj1 * 256;
            kw = *(const unsigned*)&KVh[kvb + d0];
            vw = *(const unsigned*)&KVh[kvb + 128 + d0];
            bat = battn[ekj1];
        }
        const float ae0 = aeL[bin_c * D_DIM + d0];
        const float ae1 = aeL[bin_c * D_DIM + d0 + 1];
        float k0, k1; bf2x(kw_c, k0, k1);
        float pd = (k0 + ae0) * (q0 + ae0) + (k1 + ae1) * (q1 + ae1);
        pd += __shfl_xor(pd, 1);
        pd += __shfl_xor(pd, 2);
        pd += __shfl_xor(pd, 4);
        const float ex = expf(pd * 0.25f + bat_c * dw);
        den += ex;
        float v0, v1; bf2x(vw_c, v0, v1);
        acc0 += ex * (v0 + ae0);
        acc1 += ex * (v1 + ae1);
    }
    const float inv = (den > 0.f) ? 1.f / den : 0.f;
    const int64_t base = (int64_t)e * D_DIM;
    *(unsigned*)&attf[base + d0] =
        (unsigned)f2bf(acc0 * inv) | ((unsigned)f2bf(acc1 * inv) << 16);
}

// ---------------------------------------------------------------------------
// FUSED he + LN1 + FFN (GEMM1 -> LDS -> GEMM2) + residual + LN2 -> d_out.
// Prologue: he = att + bond (registers, reused by LN2 epilogue); LN1 -> h
// (bf16) into LDS hs[64][136] (pitch keeps 16B align, spreads banks);
// GEMM1 A-fragments read from LDS.  B-REUSE layout throughout.
// ---------------------------------------------------------------------------
__launch_bounds__(256)
__global__ void ffn_fused(const unsigned short* __restrict__ attf,
                          const float* __restrict__ bond,
                          const unsigned short* __restrict__ W1t,
                          const unsigned short* __restrict__ W2t,
                          const float* __restrict__ g1, const float* __restrict__ b1,
                          const float* __restrict__ g2, const float* __restrict__ b2,
                          float* __restrict__ outp)
{
    __shared__ __align__(16) unsigned char lds[51200];
    unsigned short* hs = (unsigned short*)lds;            // [64][136] bf16
    unsigned short* ms = (unsigned short*)(lds + 17408);  // [64][264] bf16
    float (*cs)[132]   = (float(*)[132])lds;              // [64][132] f32 (aliases)
    const int lane = threadIdx.x & 63, w = threadIdx.x >> 6;
    const int base_row = blockIdx.x * 64;
    const int lr = lane & 15, g = lane >> 4;

    // ---- prologue: he = att + bond; LN1 -> hs ----
    float hev0[16], hev1[16];
    #pragma unroll
    for (int i = 0; i < 16; ++i) {
        const int64_t rg = (int64_t)(base_row + w * 16 + i) * 128;
        hev0[i] = bf2f(attf[rg + lane])      + bond[rg + lane];
        hev1[i] = bf2f(attf[rg + 64 + lane]) + bond[rg + 64 + lane];
    }
    const float g1a = g1[lane], g1b = g1[lane + 64];
    const float b1a = b1[lane], b1b = b1[lane + 64];
    #pragma unroll 2
    for (int i = 0; i < 16; ++i) {
        const int row = w * 16 + i;
        float s = hev0[i] + hev1[i];
        #pragma unroll
        for (int o = 32; o > 0; o >>= 1) s += __shfl_xor(s, o);
        const float mean = s * (1.f / 128.f);
        const float dx0 = hev0[i] - mean, dx1 = hev1[i] - mean;
        float var = dx0 * dx0 + dx1 * dx1;
        #pragma unroll
        for (int o = 32; o > 0; o >>= 1) var += __shfl_xor(var, o);
        const float rs = rsqrtf(var * (1.f / 128.f) + 1e-5f);
        hs[row * 136 + lane]      = f2bf(dx0 * rs * g1a + b1a);
        hs[row * 136 + 64 + lane] = f2bf(dx1 * rs * g1b + b1b);
    }
    __syncthreads();

    // ---- GEMM1: wave w -> cols [w*64, w*64+64), all 64 rows; K=128 ----
    {
        f32x4 acc[4][4];
        #pragma unroll
        for (int m = 0; m < 4; ++m)
            #pragma unroll
            for (int n = 0; n < 4; ++n) acc[m][n] = (f32x4){0.f, 0.f, 0.f, 0.f};
        #pragma unroll
        for (int kk = 0; kk < 4; ++kk) {
            bf16x8 a[4], b[4];
            #pragma unroll
            for (int m = 0; m < 4; ++m)
                a[m] = *(const bf16x8*)&hs[(m * 16 + lr) * 136 + kk * 32 + g * 8];
            #pragma unroll
            for (int n = 0; n < 4; ++n)
                b[n] = *(const bf16x8*)&W1t[((w * 4 + n) * 16 + lr) * 128 + kk * 32 + g * 8];
            #pragma unroll
            for (int m = 0; m < 4; ++m)
                #pragma unroll
                for (int n = 0; n < 4; ++n)
                    acc[m][n] = __builtin_amdgcn_mfma_f32_16x16x32_bf16(a[m], b[n], acc[m][n], 0, 0, 0);
        }
        #pragma unroll
        for (int m = 0; m < 4; ++m)
            #pragma unroll
            for (int n = 0; n < 4; ++n)
                #pragma unroll
                for (int r = 0; r < 4; ++r) {
                    float v = acc[m][n][r];
                    v = v > 0.f ? v : 0.f;
                    ms[(m * 16 + g * 4 + r) * 264 + (w * 4 + n) * 16 + lr] = f2bf(v);
                }
    }
    __syncthreads();

    // ---- GEMM2: wave w -> cols [w*32, w*32+32), all 64 rows; K=256 ----
    f32x4 acc2[4][2];
    #pragma unroll
    for (int m = 0; m < 4; ++m)
        #pragma unroll
        for (int n = 0; n < 2; ++n) acc2[m][n] = (f32x4){0.f, 0.f, 0.f, 0.f};
    #pragma unroll
    for (int kk = 0; kk < 8; ++kk) {
        bf16x8 a[4], b[2];
        #pragma unroll
        for (int m = 0; m < 4; ++m)
            a[m] = *(const bf16x8*)&ms[(m * 16 + lr) * 264 + kk * 32 + g * 8];
        #pragma unroll
        for (int n = 0; n < 2; ++n)
            b[n] = *(const bf16x8*)&W2t[((w * 2 + n) * 16 + lr) * 256 + kk * 32 + g * 8];
        #pragma unroll
        for (int m = 0; m < 4; ++m)
            #pragma unroll
            for (int n = 0; n < 2; ++n)
                acc2[m][n] = __builtin_amdgcn_mfma_f32_16x16x32_bf16(a[m], b[n], acc2[m][n], 0, 0, 0);
    }
    __syncthreads();   // all hs/ms reads done before cs overwrites the region
    #pragma unroll
    for (int m = 0; m < 4; ++m)
        #pragma unroll
        for (int n = 0; n < 2; ++n)
            #pragma unroll
            for (int r = 0; r < 4; ++r)
                cs[m * 16 + g * 4 + r][w * 32 + n * 16 + lr] = acc2[m][n][r];
    __syncthreads();

    // ---- residual + LN2 on the wave's own 16 rows (registers only) ----
    #pragma unroll 2
    for (int i = 0; i < 16; ++i) {
        const int row = w * 16 + i;
        const int64_t rg = (int64_t)(base_row + row) * 128;
        float x0 = cs[row][lane]      + hev0[i];
        float x1 = cs[row][64 + lane] + hev1[i];
        float s = x0 + x1;
        #pragma unroll
        for (int o = 32; o > 0; o >>= 1) s += __shfl_xor(s, o);
        const float mean = s * (1.f / 128.f);
        const float d0 = x0 - mean, d1 = x1 - mean;
        float v = d0 * d0 + d1 * d1;
        #pragma unroll
        for (int o = 32; o > 0; o >>= 1) v += __shfl_xor(v, o);
        const float rs = rsqrtf(v * (1.f / 128.f) + 1e-5f);
        outp[rg + lane]      = d0 * rs * g2[lane]      + b2[lane];
        outp[rg + 64 + lane] = d1 * rs * g2[lane + 64] + b2[lane + 64];
    }
}

// ---------------------------------------------------------------------------
extern "C" void kernel_launch(void* const* d_in, const int* in_sizes, int n_in,
                              void* d_out, int out_size, void* d_ws, size_t ws_size,
                              hipStream_t stream)
{
    const float* bond     = (const float*)d_in[0];
    const float* pos      = (const float*)d_in[1];
    const float* battn    = (const float*)d_in[2];
    const float* ang_tab  = (const float*)d_in[3];
    const float* ang_in_W = (const float*)d_in[4];
    const float* ang_in_b = (const float*)d_in[5];
    const float* ang2_W   = (const float*)d_in[6];
    const float* ang2_b   = (const float*)d_in[7];
    const float* ang1_W   = (const float*)d_in[8];
    const float* ang1_b   = (const float*)d_in[9];
    const float* k_W      = (const float*)d_in[10];
    const float* q_W      = (const float*)d_in[11];
    const float* v_W      = (const float*)d_in[12];
    const float* dis_W    = (const float*)d_in[13];
    const float* ffn_W1   = (const float*)d_in[14];
    const float* ffn_W2   = (const float*)d_in[15];
    const float* ln1_g    = (const float*)d_in[16];
    const float* ln1_b    = (const float*)d_in[17];
    const float* ln2_g    = (const float*)d_in[18];
    const float* ln2_b    = (const float*)d_in[19];
    const int*   index_kj = (const int*)d_in[20];
    const int*   index_ji = (const int*)d_in[21];
    const int*   idx_i    = (const int*)d_in[22];
    const int*   idx_j    = (const int*)d_in[23];
    const int*   idx_k    = (const int*)d_in[24];

    float* ws = (float*)d_ws;
    // ws layout (float offsets) — ~110 MB, no overlaps
    int*            bins  = (int*)(ws + 0);          //   400,000
    int*            slot  = (int*)(ws + 400000);     //   400,000
    int*            offs  = (int*)(ws + 800000);     //   200,000
    int*            cnt   = (int*)(ws + 1000000);    //   200,000
    int*            cur   = (int*)(ws + 1200000);    //   200,000 (contiguous w/ cnt)
    int*            bsum  = (int*)(ws + 1400000);    //     1,024
    float*          aeT   = ws + 1401088;            //       768
    unsigned short* W1t   = (unsigned short*)(ws + 1401856);   // 32,768 us
    unsigned short* W2t   = (unsigned short*)(ws + 1418240);   // 32,768 us
    unsigned short* Wt    = (unsigned short*)(ws + 1434624);   // 49,152 us
    unsigned short* attf  = (unsigned short*)(ws + 1459200);   // 25.6M us
    unsigned short* Qh    = (unsigned short*)(ws + 14259200);  // 25.6M us

    // d_out holds KVh (E x 256 bf16 = exactly out bytes), then final out
    unsigned short* KVh = (unsigned short*)d_out;
    float*          out = (float*)d_out;

    hipMemsetAsync(cnt, 0, (size_t)2 * E_EDGES * sizeof(int), stream);  // cnt+cur

    ang_mlp_kernel<<<1, 256, 0, stream>>>(ang_tab, ang_in_W, ang_in_b,
                                          ang2_W, ang2_b, ang1_W, ang1_b, aeT);
    conv_w_kernel<<<192, 256, 0, stream>>>(k_W, q_W, v_W, ffn_W1, ffn_W2, Wt, W1t, W2t);
    tri_bins_kernel<<<(T_TRI + 255) / 256, 256, 0, stream>>>(
        pos, idx_i, idx_j, idx_k, index_ji, bins, cnt);

    const int NB = (E_EDGES + 255) / 256;    // 782
    scan1_kernel<<<NB, 256, 0, stream>>>(cnt, offs, bsum);
    scan2_kernel<<<1, 1024, 0, stream>>>(bsum, NB);
    scan3_kernel<<<NB, 256, 0, stream>>>(offs, bsum);
    fill_kernel<<<(T_TRI + 255) / 256, 256, 0, stream>>>(index_ji, offs, cur, slot);

    proj_mfma<<<E_EDGES / 64, 256, 0, stream>>>(bond, Wt, KVh, Qh);

    edge_att_kernel<<<E_EDGES / 4, 256, 0, stream>>>(
        KVh, Qh, aeT, bins, index_kj, slot, offs, cnt, battn, dis_W, attf);

    ffn_fused<<<E_EDGES / 64, 256, 0, stream>>>(attf, bond, W1t, W2t,
                                                ln1_g, ln1_b, ln2_g, ln2_b, out);
}

// Round 26
// 494.393 us; speedup vs baseline: 1.6014x; 1.0629x over previous
//
#include <hip/hip_runtime.h>
#include <cstdint>
#include <math.h>

// Problem constants (match reference)
#define N_ATOMS 30000
#define E_EDGES 200000
#define T_TRI   400000
#define D_DIM   128
#define H_HEADS 8
#define F_FEAT  16
#define CLS     6

typedef __attribute__((ext_vector_type(8))) short bf16x8;
typedef __attribute__((ext_vector_type(4))) float f32x4;

// bf16 helpers (RNE pack, bit-shift unpack)
static __device__ __forceinline__ unsigned short f2bf(float f) {
    union { float f; unsigned u; } v; v.f = f;
    unsigned r = v.u + 0x7FFFu + ((v.u >> 16) & 1u);
    return (unsigned short)(r >> 16);
}
static __device__ __forceinline__ void bf2x(unsigned u, float& a, float& b) {
    union { unsigned u; float f; } x, y;
    x.u = u << 16; y.u = u & 0xFFFF0000u;
    a = x.f; b = y.f;
}
static __device__ __forceinline__ float bf2f(unsigned short u) {
    union { unsigned u; float f; } x; x.u = ((unsigned)u) << 16; return x.f;
}

// ---------------------------------------------------------------------------
// Kernel 1: 6-row angle MLP -> ae_table[6][128]
// ---------------------------------------------------------------------------
__launch_bounds__(256)
__global__ void ang_mlp_kernel(const float* __restrict__ tab,
                               const float* __restrict__ W0, const float* __restrict__ b0,
                               const float* __restrict__ W1, const float* __restrict__ b1,
                               const float* __restrict__ W2, const float* __restrict__ b2,
                               float* __restrict__ out)
{
    __shared__ float bufA[CLS * D_DIM];
    __shared__ float bufB[CLS * D_DIM];
    __shared__ float Wl[D_DIM * D_DIM];
    const int tid = threadIdx.x;
    for (int i = tid; i < CLS * D_DIM; i += 256) bufA[i] = tab[i];
    const float* Ws[3] = {W0, W1, W2};
    const float* bs[3] = {b0, b1, b2};
    float* in  = bufA;
    float* ob  = bufB;
    for (int l = 0; l < 3; ++l) {
        __syncthreads();
        for (int i = tid * 4; i < D_DIM * D_DIM; i += 256 * 4)
            *(float4*)&Wl[i] = *(const float4*)&Ws[l][i];
        __syncthreads();
        for (int o = tid; o < CLS * D_DIM; o += 256) {
            const int r = o >> 7, c = o & 127;
            float acc = bs[l][c];
            #pragma unroll 8
            for (int k = 0; k < D_DIM; ++k) acc += in[r * D_DIM + k] * Wl[k * D_DIM + c];
            ob[o] = fmaxf(acc, 0.f);
        }
        float* t = in; in = ob; ob = t;
    }
    __syncthreads();
    for (int i = tid; i < CLS * D_DIM; i += 256) out[i] = in[i];
}

// ---------------------------------------------------------------------------
// Kernel 2: bins (with atan2(+0,-0) degenerate-sign fix) + per-edge count.
// ---------------------------------------------------------------------------
__launch_bounds__(256)
__global__ void tri_bins_kernel(const float* __restrict__ pos,
                                const int* __restrict__ idx_i,
                                const int* __restrict__ idx_j,
                                const int* __restrict__ idx_k,
                                const int* __restrict__ iji,
                                int* __restrict__ bins,
                                int* __restrict__ cnt)
{
    const int t = blockIdx.x * 256 + threadIdx.x;
    if (t >= T_TRI) return;
    const int ii = idx_i[t], jj = idx_j[t], kk = idx_k[t];
    const float pix = pos[3*ii], piy = pos[3*ii+1], piz = pos[3*ii+2];
    const float jx = __fsub_rn(pos[3*jj],   pix);
    const float jy = __fsub_rn(pos[3*jj+1], piy);
    const float jz = __fsub_rn(pos[3*jj+2], piz);
    const float kx = __fsub_rn(pos[3*kk],   pix);
    const float ky = __fsub_rn(pos[3*kk+1], piy);
    const float kz = __fsub_rn(pos[3*kk+2], piz);
    const float a  = __fadd_rn(__fadd_rn(__fmul_rn(jx,kx), __fmul_rn(jy,ky)),
                               __fmul_rn(jz,kz));
    const float cx = __fsub_rn(__fmul_rn(jy,kz), __fmul_rn(jz,ky));
    const float cy = __fsub_rn(__fmul_rn(jz,kx), __fmul_rn(jx,kz));
    const float cz = __fsub_rn(__fmul_rn(jx,ky), __fmul_rn(jy,kx));
    const float ss = __fadd_rn(__fadd_rn(__fmul_rn(cx,cx), __fmul_rn(cy,cy)),
                               __fmul_rn(cz,cz));
    const float b  = __fsqrt_rn(ss);

    int bin;
    if (b == 0.0f && __float_as_uint(a) == 0x80000000u) {
        bin = 0;   // atan2(+0,-0): IEEE pi (bin 5) vs reference SVML 0 (bin 0)
    } else {
        const float angle = (float)atan2((double)b, (double)a);
        const float c = (float)(3.1415926 / 6.0);
        const float q = __fdiv_rn(angle, c);
        bin = (int)q;
        bin = bin < 0 ? 0 : (bin > CLS - 1 ? CLS - 1 : bin);
    }
    bins[t] = bin;
    atomicAdd(&cnt[iji[t]], 1);
}

// ---------------------------------------------------------------------------
// CSR build: block-scan (3 kernels) + scatter fill
// ---------------------------------------------------------------------------
__launch_bounds__(256)
__global__ void scan1_kernel(const int* __restrict__ cnt, int* __restrict__ offs,
                             int* __restrict__ bsum)
{
    __shared__ int buf[256];
    const int i = blockIdx.x * 256 + threadIdx.x;
    const int v = (i < E_EDGES) ? cnt[i] : 0;
    buf[threadIdx.x] = v;
    __syncthreads();
    for (int o = 1; o < 256; o <<= 1) {
        const int t = (threadIdx.x >= o) ? buf[threadIdx.x - o] : 0;
        __syncthreads();
        buf[threadIdx.x] += t;
        __syncthreads();
    }
    if (i < E_EDGES) offs[i] = buf[threadIdx.x] - v;
    if (threadIdx.x == 255) bsum[blockIdx.x] = buf[255];
}

__launch_bounds__(1024)
__global__ void scan2_kernel(int* __restrict__ bsum, int nb)
{
    __shared__ int buf[1024];
    const int tid = threadIdx.x;
    const int v = (tid < nb) ? bsum[tid] : 0;
    buf[tid] = v;
    __syncthreads();
    for (int o = 1; o < 1024; o <<= 1) {
        const int t = (tid >= o) ? buf[tid - o] : 0;
        __syncthreads();
        buf[tid] += t;
        __syncthreads();
    }
    if (tid < nb) bsum[tid] = buf[tid] - v;   // exclusive
}

__launch_bounds__(256)
__global__ void scan3_kernel(int* __restrict__ offs, const int* __restrict__ bsum)
{
    const int i = blockIdx.x * 256 + threadIdx.x;
    if (i < E_EDGES) offs[i] += bsum[blockIdx.x];
}

__launch_bounds__(256)
__global__ void fill_kernel(const int* __restrict__ iji, const int* __restrict__ offs,
                            int* __restrict__ cur, int* __restrict__ slot)
{
    const int t = blockIdx.x * 256 + threadIdx.x;
    if (t >= T_TRI) return;
    const int e = iji[t];
    const int p = offs[e] + atomicAdd(&cur[e], 1);
    slot[p] = t;
}

// ---------------------------------------------------------------------------
// Weight convert: Wt[384][128] = [kW|qW|vW]^T bf16;  W1t[256][128], W2t[128][256]
// ---------------------------------------------------------------------------
__launch_bounds__(256)
__global__ void conv_w_kernel(const float* __restrict__ kW, const float* __restrict__ qW,
                              const float* __restrict__ vW,
                              const float* __restrict__ W1, const float* __restrict__ W2,
                              unsigned short* __restrict__ Wt,
                              unsigned short* __restrict__ W1t,
                              unsigned short* __restrict__ W2t)
{
    const int i = blockIdx.x * 256 + threadIdx.x;
    if (i < 384 * 128) {               // Wt[n][k]
        const int n = i >> 7, k = i & 127;
        const int sel = n >> 7, c = n & 127;
        const float* W = (sel == 0) ? kW : (sel == 1) ? qW : vW;
        Wt[i] = f2bf(W[k * 128 + c]);
    }
    if (i < 128 * 256) {
        { const int n = i >> 7, k = i & 127;  W1t[n * 128 + k] = f2bf(W1[k * 256 + n]); }
        { const int n = i >> 8, k = i & 255;  W2t[n * 256 + k] = f2bf(W2[k * 128 + n]); }
    }
}

// ---------------------------------------------------------------------------
// Fused K/Q/V projection (MFMA) with B-REUSE (proven R22/R23).
// Output: KVh[E][256] (K cols 0-127, V cols 128-255), Qh[E][128].
// ---------------------------------------------------------------------------
__launch_bounds__(256)
__global__ void proj_mfma(const float* __restrict__ bond,
                          const unsigned short* __restrict__ Wt,
                          unsigned short* __restrict__ KVh,
                          unsigned short* __restrict__ Qh)
{
    __shared__ unsigned short ms[64 * 392];   // pitch 392 breaks bank alias
    const int lane = threadIdx.x & 63, w = threadIdx.x >> 6;
    const int base_row = blockIdx.x * 64;
    const int lr = lane & 15, g = lane >> 4;
    f32x4 acc[4][6];
    #pragma unroll
    for (int m = 0; m < 4; ++m)
        #pragma unroll
        for (int n = 0; n < 6; ++n) acc[m][n] = (f32x4){0.f, 0.f, 0.f, 0.f};
    #pragma unroll
    for (int kk = 0; kk < 4; ++kk) {
        bf16x8 a[4], b[6];
        #pragma unroll
        for (int m = 0; m < 4; ++m) {
            const int64_t ab = (int64_t)(base_row + m * 16 + lr) * 128 + kk * 32 + g * 8;
            const float4 f0 = *(const float4*)&bond[ab];
            const float4 f1 = *(const float4*)&bond[ab + 4];
            a[m][0] = (short)f2bf(f0.x); a[m][1] = (short)f2bf(f0.y);
            a[m][2] = (short)f2bf(f0.z); a[m][3] = (short)f2bf(f0.w);
            a[m][4] = (short)f2bf(f1.x); a[m][5] = (short)f2bf(f1.y);
            a[m][6] = (short)f2bf(f1.z); a[m][7] = (short)f2bf(f1.w);
        }
        #pragma unroll
        for (int n = 0; n < 6; ++n)
            b[n] = *(const bf16x8*)&Wt[((w * 6 + n) * 16 + lr) * 128 + kk * 32 + g * 8];
        #pragma unroll
        for (int m = 0; m < 4; ++m)
            #pragma unroll
            for (int n = 0; n < 6; ++n)
                acc[m][n] = __builtin_amdgcn_mfma_f32_16x16x32_bf16(a[m], b[n], acc[m][n], 0, 0, 0);
    }
    #pragma unroll
    for (int m = 0; m < 4; ++m)
        #pragma unroll
        for (int n = 0; n < 6; ++n)
            #pragma unroll
            for (int r = 0; r < 4; ++r)
                ms[(m * 16 + g * 4 + r) * 392 + (w * 6 + n) * 16 + lr] = f2bf(acc[m][n][r]);
    __syncthreads();
    // cols 0-127 = K -> KV[0..127]; 128-255 = Q -> Q; 256-383 = V -> KV[128..255]
    for (int idx = threadIdx.x; idx < 64 * 48; idx += 256) {
        const int row = idx / 48, c8 = (idx % 48) * 8;
        const int e = base_row + row;
        const uint4 v = *(const uint4*)&ms[row * 392 + c8];
        if (c8 < 128)       *(uint4*)&KVh[(int64_t)e * 256 + c8] = v;
        else if (c8 < 256)  *(uint4*)&Qh[(int64_t)e * 128 + (c8 - 128)] = v;
        else                *(uint4*)&KVh[(int64_t)e * 256 + 128 + (c8 - 256)] = v;
    }
}

// ---------------------------------------------------------------------------
// FUSED per-edge attention + aggregation -> attf (bf16, normalized att out).
// Triplet loop software-pipelined.
// ---------------------------------------------------------------------------
__launch_bounds__(256)
__global__ void edge_att_kernel(const unsigned short* __restrict__ KVh,
                                const unsigned short* __restrict__ Qh,
                                const float* __restrict__ aeT,
                                const int* __restrict__ bins,
                                const int* __restrict__ ikj,
                                const int* __restrict__ slot,
                                const int* __restrict__ offs,
                                const int* __restrict__ cnt,
                                const float* __restrict__ battn,
                                const float* __restrict__ disW,
                                unsigned short* __restrict__ attf)
{
    __shared__ float aeL[CLS * D_DIM];
    for (int i = threadIdx.x; i < CLS * D_DIM; i += 256) aeL[i] = aeT[i];
    __syncthreads();
    const int wid  = threadIdx.x >> 6;
    const int lane = threadIdx.x & 63;
    const int e = blockIdx.x * 4 + wid;
    const int d0 = lane * 2;
    const int h  = lane >> 3;
    const float dw = disW[h];

    unsigned qw = *(const unsigned*)&Qh[(int64_t)e * D_DIM + d0];
    float q0, q1; bf2x(qw, q0, q1);

    float acc0 = 0.f, acc1 = 0.f, den = 0.f;
    const int start = offs[e], n = cnt[e];
    int bin = 0; unsigned kw = 0, vw = 0; float bat = 0.f;
    if (n > 0) {
        const int t0 = slot[start];
        bin = bins[t0];
        const int ekj0 = ikj[t0];
        const int64_t kvb = (int64_t)ekj0 * 256;
        kw = *(const unsigned*)&KVh[kvb + d0];
        vw = *(const unsigned*)&KVh[kvb + 128 + d0];
        bat = battn[ekj0];
    }
    for (int s = 0; s < n; ++s) {
        const int bin_c = bin;
        const unsigned kw_c = kw, vw_c = vw;
        const float bat_c = bat;
        if (s + 1 < n) {                       // prefetch next triplet
            const int t1 = slot[start + s + 1];
            bin = bins[t1];
            const int ekj1 = ikj[t1];
            const int64_t kvb = (int64_t)ekj1 * 256;
            kw = *(const unsigned*)&KVh[kvb + d0];
            vw = *(const unsigned*)&KVh[kvb + 128 + d0];
            bat = battn[ekj1];
        }
        const float ae0 = aeL[bin_c * D_DIM + d0];
        const float ae1 = aeL[bin_c * D_DIM + d0 + 1];
        float k0, k1; bf2x(kw_c, k0, k1);
        float pd = (k0 + ae0) * (q0 + ae0) + (k1 + ae1) * (q1 + ae1);
        pd += __shfl_xor(pd, 1);
        pd += __shfl_xor(pd, 2);
        pd += __shfl_xor(pd, 4);
        const float ex = expf(pd * 0.25f + bat_c * dw);
        den += ex;
        float v0, v1; bf2x(vw_c, v0, v1);
        acc0 += ex * (v0 + ae0);
        acc1 += ex * (v1 + ae1);
    }
    const float inv = (den > 0.f) ? 1.f / den : 0.f;
    const int64_t base = (int64_t)e * D_DIM;
    *(unsigned*)&attf[base + d0] =
        (unsigned)f2bf(acc0 * inv) | ((unsigned)f2bf(acc1 * inv) << 16);
}

// ---------------------------------------------------------------------------
// FUSED he + LN1 + FFN (GEMM1 -> LDS -> GEMM2) + residual + LN2 -> d_out.
// LN reductions use INDEPENDENT sum / sum-of-squares shfl chains
// (var = E[x^2] - mean^2) with 4-row unroll -> halves serial shfl depth
// (R25: ffn was shfl-dependency-latency bound at MfmaUtil 5.7%).
// ---------------------------------------------------------------------------
__launch_bounds__(256)
__global__ void ffn_fused(const unsigned short* __restrict__ attf,
                          const float* __restrict__ bond,
                          const unsigned short* __restrict__ W1t,
                          const unsigned short* __restrict__ W2t,
                          const float* __restrict__ g1, const float* __restrict__ b1,
                          const float* __restrict__ g2, const float* __restrict__ b2,
                          float* __restrict__ outp)
{
    __shared__ __align__(16) unsigned char lds[51200];
    unsigned short* hs = (unsigned short*)lds;            // [64][136] bf16
    unsigned short* ms = (unsigned short*)(lds + 17408);  // [64][264] bf16
    float (*cs)[132]   = (float(*)[132])lds;              // [64][132] f32 (aliases)
    const int lane = threadIdx.x & 63, w = threadIdx.x >> 6;
    const int base_row = blockIdx.x * 64;
    const int lr = lane & 15, g = lane >> 4;

    // ---- prologue: he = att + bond; LN1 -> hs ----
    float hev0[16], hev1[16];
    #pragma unroll
    for (int i = 0; i < 16; ++i) {
        const int64_t rg = (int64_t)(base_row + w * 16 + i) * 128;
        hev0[i] = bf2f(attf[rg + lane])      + bond[rg + lane];
        hev1[i] = bf2f(attf[rg + 64 + lane]) + bond[rg + 64 + lane];
    }
    const float g1a = g1[lane], g1b = g1[lane + 64];
    const float b1a = b1[lane], b1b = b1[lane + 64];
    #pragma unroll 4
    for (int i = 0; i < 16; ++i) {
        const int row = w * 16 + i;
        const float x0 = hev0[i], x1 = hev1[i];
        float s  = x0 + x1;
        float q  = x0 * x0 + x1 * x1;
        #pragma unroll
        for (int o = 32; o > 0; o >>= 1) {   // independent chains, interleaved
            s += __shfl_xor(s, o);
            q += __shfl_xor(q, o);
        }
        const float mean = s * (1.f / 128.f);
        const float var  = q * (1.f / 128.f) - mean * mean;
        const float rs = rsqrtf(var + 1e-5f);
        hs[row * 136 + lane]      = f2bf((x0 - mean) * rs * g1a + b1a);
        hs[row * 136 + 64 + lane] = f2bf((x1 - mean) * rs * g1b + b1b);
    }
    __syncthreads();

    // ---- GEMM1: wave w -> cols [w*64, w*64+64), all 64 rows; K=128 ----
    {
        f32x4 acc[4][4];
        #pragma unroll
        for (int m = 0; m < 4; ++m)
            #pragma unroll
            for (int n = 0; n < 4; ++n) acc[m][n] = (f32x4){0.f, 0.f, 0.f, 0.f};
        #pragma unroll
        for (int kk = 0; kk < 4; ++kk) {
            bf16x8 a[4], b[4];
            #pragma unroll
            for (int m = 0; m < 4; ++m)
                a[m] = *(const bf16x8*)&hs[(m * 16 + lr) * 136 + kk * 32 + g * 8];
            #pragma unroll
            for (int n = 0; n < 4; ++n)
                b[n] = *(const bf16x8*)&W1t[((w * 4 + n) * 16 + lr) * 128 + kk * 32 + g * 8];
            #pragma unroll
            for (int m = 0; m < 4; ++m)
                #pragma unroll
                for (int n = 0; n < 4; ++n)
                    acc[m][n] = __builtin_amdgcn_mfma_f32_16x16x32_bf16(a[m], b[n], acc[m][n], 0, 0, 0);
        }
        #pragma unroll
        for (int m = 0; m < 4; ++m)
            #pragma unroll
            for (int n = 0; n < 4; ++n)
                #pragma unroll
                for (int r = 0; r < 4; ++r) {
                    float v = acc[m][n][r];
                    v = v > 0.f ? v : 0.f;
                    ms[(m * 16 + g * 4 + r) * 264 + (w * 4 + n) * 16 + lr] = f2bf(v);
                }
    }
    __syncthreads();

    // ---- GEMM2: wave w -> cols [w*32, w*32+32), all 64 rows; K=256 ----
    f32x4 acc2[4][2];
    #pragma unroll
    for (int m = 0; m < 4; ++m)
        #pragma unroll
        for (int n = 0; n < 2; ++n) acc2[m][n] = (f32x4){0.f, 0.f, 0.f, 0.f};
    #pragma unroll
    for (int kk = 0; kk < 8; ++kk) {
        bf16x8 a[4], b[2];
        #pragma unroll
        for (int m = 0; m < 4; ++m)
            a[m] = *(const bf16x8*)&ms[(m * 16 + lr) * 264 + kk * 32 + g * 8];
        #pragma unroll
        for (int n = 0; n < 2; ++n)
            b[n] = *(const bf16x8*)&W2t[((w * 2 + n) * 16 + lr) * 256 + kk * 32 + g * 8];
        #pragma unroll
        for (int m = 0; m < 4; ++m)
            #pragma unroll
            for (int n = 0; n < 2; ++n)
                acc2[m][n] = __builtin_amdgcn_mfma_f32_16x16x32_bf16(a[m], b[n], acc2[m][n], 0, 0, 0);
    }
    __syncthreads();   // all hs/ms reads done before cs overwrites the region
    #pragma unroll
    for (int m = 0; m < 4; ++m)
        #pragma unroll
        for (int n = 0; n < 2; ++n)
            #pragma unroll
            for (int r = 0; r < 4; ++r)
                cs[m * 16 + g * 4 + r][w * 32 + n * 16 + lr] = acc2[m][n][r];
    __syncthreads();

    // ---- residual + LN2 on the wave's own 16 rows ----
    const float g2a = g2[lane], g2b = g2[lane + 64];
    const float b2a = b2[lane], b2b = b2[lane + 64];
    #pragma unroll 4
    for (int i = 0; i < 16; ++i) {
        const int row = w * 16 + i;
        const int64_t rg = (int64_t)(base_row + row) * 128;
        const float x0 = cs[row][lane]      + hev0[i];
        const float x1 = cs[row][64 + lane] + hev1[i];
        float s = x0 + x1;
        float q = x0 * x0 + x1 * x1;
        #pragma unroll
        for (int o = 32; o > 0; o >>= 1) {
            s += __shfl_xor(s, o);
            q += __shfl_xor(q, o);
        }
        const float mean = s * (1.f / 128.f);
        const float var  = q * (1.f / 128.f) - mean * mean;
        const float rs = rsqrtf(var + 1e-5f);
        outp[rg + lane]      = (x0 - mean) * rs * g2a + b2a;
        outp[rg + 64 + lane] = (x1 - mean) * rs * g2b + b2b;
    }
}

// ---------------------------------------------------------------------------
extern "C" void kernel_launch(void* const* d_in, const int* in_sizes, int n_in,
                              void* d_out, int out_size, void* d_ws, size_t ws_size,
                              hipStream_t stream)
{
    const float* bond     = (const float*)d_in[0];
    const float* pos      = (const float*)d_in[1];
    const float* battn    = (const float*)d_in[2];
    const float* ang_tab  = (const float*)d_in[3];
    const float* ang_in_W = (const float*)d_in[4];
    const float* ang_in_b = (const float*)d_in[5];
    const float* ang2_W   = (const float*)d_in[6];
    const float* ang2_b   = (const float*)d_in[7];
    const float* ang1_W   = (const float*)d_in[8];
    const float* ang1_b   = (const float*)d_in[9];
    const float* k_W      = (const float*)d_in[10];
    const float* q_W      = (const float*)d_in[11];
    const float* v_W      = (const float*)d_in[12];
    const float* dis_W    = (const float*)d_in[13];
    const float* ffn_W1   = (const float*)d_in[14];
    const float* ffn_W2   = (const float*)d_in[15];
    const float* ln1_g    = (const float*)d_in[16];
    const float* ln1_b    = (const float*)d_in[17];
    const float* ln2_g    = (const float*)d_in[18];
    const float* ln2_b    = (const float*)d_in[19];
    const int*   index_kj = (const int*)d_in[20];
    const int*   index_ji = (const int*)d_in[21];
    const int*   idx_i    = (const int*)d_in[22];
    const int*   idx_j    = (const int*)d_in[23];
    const int*   idx_k    = (const int*)d_in[24];

    float* ws = (float*)d_ws;
    // ws layout (float offsets) — ~110 MB, no overlaps
    int*            bins  = (int*)(ws + 0);          //   400,000
    int*            slot  = (int*)(ws + 400000);     //   400,000
    int*            offs  = (int*)(ws + 800000);     //   200,000
    int*            cnt   = (int*)(ws + 1000000);    //   200,000
    int*            cur   = (int*)(ws + 1200000);    //   200,000 (contiguous w/ cnt)
    int*            bsum  = (int*)(ws + 1400000);    //     1,024
    float*          aeT   = ws + 1401088;            //       768
    unsigned short* W1t   = (unsigned short*)(ws + 1401856);   // 32,768 us
    unsigned short* W2t   = (unsigned short*)(ws + 1418240);   // 32,768 us
    unsigned short* Wt    = (unsigned short*)(ws + 1434624);   // 49,152 us
    unsigned short* attf  = (unsigned short*)(ws + 1459200);   // 25.6M us
    unsigned short* Qh    = (unsigned short*)(ws + 14259200);  // 25.6M us

    // d_out holds KVh (E x 256 bf16 = exactly out bytes), then final out
    unsigned short* KVh = (unsigned short*)d_out;
    float*          out = (float*)d_out;

    hipMemsetAsync(cnt, 0, (size_t)2 * E_EDGES * sizeof(int), stream);  // cnt+cur

    ang_mlp_kernel<<<1, 256, 0, stream>>>(ang_tab, ang_in_W, ang_in_b,
                                          ang2_W, ang2_b, ang1_W, ang1_b, aeT);
    conv_w_kernel<<<192, 256, 0, stream>>>(k_W, q_W, v_W, ffn_W1, ffn_W2, Wt, W1t, W2t);
    tri_bins_kernel<<<(T_TRI + 255) / 256, 256, 0, stream>>>(
        pos, idx_i, idx_j, idx_k, index_ji, bins, cnt);

    const int NB = (E_EDGES + 255) / 256;    // 782
    scan1_kernel<<<NB, 256, 0, stream>>>(cnt, offs, bsum);
    scan2_kernel<<<1, 1024, 0, stream>>>(bsum, NB);
    scan3_kernel<<<NB, 256, 0, stream>>>(offs, bsum);
    fill_kernel<<<(T_TRI + 255) / 256, 256, 0, stream>>>(index_ji, offs, cur, slot);

    proj_mfma<<<E_EDGES / 64, 256, 0, stream>>>(bond, Wt, KVh, Qh);

    edge_att_kernel<<<E_EDGES / 4, 256, 0, stream>>>(
        KVh, Qh, aeT, bins, index_kj, slot, offs, cnt, battn, dis_W, attf);

    ffn_fused<<<E_EDGES / 64, 256, 0, stream>>>(attf, bond, W1t, W2t,
                                                ln1_g, ln1_b, ln2_g, ln2_b, out);
}